// Round 17
// baseline (146.663 us; speedup 1.0000x reference)
//
#include <hip/hip_runtime.h>
#include <hip/hip_bf16.h>

typedef __bf16 bf16x8 __attribute__((ext_vector_type(8)));
typedef __bf16 bf16x4 __attribute__((ext_vector_type(4)));
typedef float  f32x4  __attribute__((ext_vector_type(4)));

#define MFMA16(a, b, c) __builtin_amdgcn_mfma_f32_16x16x32_bf16((a), (b), (c), 0, 0, 0)

typedef const __attribute__((address_space(1))) unsigned int* gas_t;
typedef __attribute__((address_space(3))) unsigned int* las_t;
// DMA global->LDS, 16B/lane, linear LDS dest (base + lane*16).
__device__ __forceinline__ void dma16(const __bf16* g, __bf16* l) {
    __builtin_amdgcn_global_load_lds((gas_t)g, (las_t)l, 16, 0, 0);
}

// Problem constants: B=8, N=1024, D=512, H=8, DH=64

// ---------------------------------------------------------------------------
// Kernel 1: fused QKV projection — ONE pass over x serves all 3 weights.
// ---------------------------------------------------------------------------
__global__ __launch_bounds__(256) void gemm_qkv(
    const float* __restrict__ x,
    const float* __restrict__ Wq, const float* __restrict__ Wk,
    const float* __restrict__ Wv,
    __bf16* __restrict__ qo, __bf16* __restrict__ ko, __bf16* __restrict__ vto)
{
    __shared__ __bf16 As[64][40];
    __shared__ __bf16 Bs[3][64][40];
    const int tid  = threadIdx.x;
    const int lane = tid & 63;
    const int wid  = tid >> 6;
    const int g    = lane >> 4, l16 = lane & 15;
    const int wr   = wid >> 1,  wc  = wid & 1;
    const int r0   = blockIdx.x * 64;
    const int c0   = blockIdx.y * 64;
    const float* Ws[3] = { Wq, Wk, Wv };

    const int sr  = tid >> 3;
    const int scq = tid & 7;

    f32x4 acc[3][2][2] = {};

    for (int k0 = 0; k0 < 512; k0 += 32) {
        __syncthreads();
#pragma unroll
        for (int j = 0; j < 2; ++j) {
            const int r = sr + 32 * j;
            float4 av = *reinterpret_cast<const float4*>(x + (size_t)(r0 + r) * 512 + k0 + scq * 4);
            bf16x4 ap = { (__bf16)av.x, (__bf16)av.y, (__bf16)av.z, (__bf16)av.w };
            *reinterpret_cast<bf16x4*>(&As[r][scq * 4]) = ap;
#pragma unroll
            for (int widx = 0; widx < 3; ++widx) {
                float4 bv = *reinterpret_cast<const float4*>(Ws[widx] + (size_t)(c0 + r) * 512 + k0 + scq * 4);
                bf16x4 bp = { (__bf16)bv.x, (__bf16)bv.y, (__bf16)bv.z, (__bf16)bv.w };
                *reinterpret_cast<bf16x4*>(&Bs[widx][r][scq * 4]) = bp;
            }
        }
        __syncthreads();
        bf16x8 af[2];
#pragma unroll
        for (int rt = 0; rt < 2; ++rt)
            af[rt] = *reinterpret_cast<const bf16x8*>(&As[wr * 32 + rt * 16 + l16][g * 8]);
#pragma unroll
        for (int widx = 0; widx < 3; ++widx) {
            bf16x8 bfr[2];
#pragma unroll
            for (int ct = 0; ct < 2; ++ct)
                bfr[ct] = *reinterpret_cast<const bf16x8*>(&Bs[widx][wc * 32 + ct * 16 + l16][g * 8]);
#pragma unroll
            for (int rt = 0; rt < 2; ++rt)
#pragma unroll
                for (int ct = 0; ct < 2; ++ct)
                    acc[widx][rt][ct] = MFMA16(af[rt], bfr[ct], acc[widx][rt][ct]);
        }
    }

#pragma unroll
    for (int widx = 0; widx < 2; ++widx) {
        __bf16* dst = (widx == 0) ? qo : ko;
        const float scale = (widx == 0) ? 0.125f : 1.0f;
#pragma unroll
        for (int rt = 0; rt < 2; ++rt)
#pragma unroll
            for (int ct = 0; ct < 2; ++ct)
#pragma unroll
                for (int reg = 0; reg < 4; ++reg) {
                    int r = r0 + wr * 32 + rt * 16 + 4 * g + reg;
                    int c = c0 + wc * 32 + ct * 16 + l16;
                    float val = acc[widx][rt][ct][reg] * scale;
                    int b = r >> 10, n = r & 1023, h = c >> 6, dh = c & 63;
                    dst[(((size_t)b * 8 + h) * 1024 + n) * 64 + dh] = (__bf16)val;
                }
    }
#pragma unroll
    for (int rt = 0; rt < 2; ++rt)
#pragma unroll
        for (int ct = 0; ct < 2; ++ct) {
            int r = r0 + wr * 32 + rt * 16 + 4 * g;
            int c = c0 + wc * 32 + ct * 16 + l16;
            int b = r >> 10, n = r & 1023, h = c >> 6, dh = c & 63;
            bf16x4 pv = { (__bf16)acc[2][rt][ct][0], (__bf16)acc[2][rt][ct][1],
                          (__bf16)acc[2][rt][ct][2], (__bf16)acc[2][rt][ct][3] };
            *reinterpret_cast<bf16x4*>(vto + (((size_t)b * 8 + h) * 64 + dh) * 1024 + n) = pv;
        }
}

// ---------------------------------------------------------------------------
// Kernel 2: fused flash attention v11 = v10 with PLAIN bias loads (nt A/B).
// 8 waves = 8 heads, 32 Q-rows, grid (8 b, 32 nt), 1 block/CU, 16 rounds.
// ---------------------------------------------------------------------------
__global__ __launch_bounds__(512) void attn_v11(
    const __bf16* __restrict__ qw, const __bf16* __restrict__ kw,
    const __bf16* __restrict__ vtw, const float* __restrict__ bias,
    __bf16* __restrict__ ow)
{
    __shared__ __align__(16) __bf16 Ks[8][64][64];   // 64 KB swizzled content
    __shared__ __align__(16) __bf16 bsm[8 * 2178];   // 34.8 KB [h][m64][n34]
    __shared__ __align__(16) __bf16 psm[8 * 2178];   // 34.8 KB [w][n32][m68]
    const int tid  = threadIdx.x;
    const int w    = tid >> 6;             // head
    const int lane = tid & 63;
    const int g    = lane >> 4, l16 = lane & 15;
    const int b    = blockIdx.x;
    const int n0   = blockIdx.y * 32;
    const size_t bhs = (size_t)b * 8 + w;

    const __bf16* kbase  = kw  + bhs * 1024 * 64;
    const __bf16* vbase  = vtw + bhs * 64 * 1024;
    const float*  bias_b = bias + ((size_t)(b * 1024 + n0)) * 8192;

    const int snr = tid >> 4;     // bias n-row 0..31 (16 thr/row)
    const int sf  = tid & 15;     // f32x4 chunk base (row tile = 128 chunks)

    const int k_row  = lane >> 3;
    const int k_csrc = (lane & 7) ^ (k_row & 7);

    bf16x8 qf[2][2];
#pragma unroll
    for (int rf = 0; rf < 2; ++rf)
#pragma unroll
        for (int kc = 0; kc < 2; ++kc)
            qf[rf][kc] = *reinterpret_cast<const bf16x8*>(
                qw + (bhs * 1024 + n0 + rf * 16 + l16) * 64 + kc * 32 + g * 8);

    f32x4 o[2][4] = {};
    float lrun[2][4] = {};

    f32x4 bp[8];   // one bias round (32n x 64m x 8h) / 512 thr = 8 f32x4

#define LOAD_BIAS(tt)                                                          \
    {                                                                          \
        const int m0_ = (tt) * 64;                                             \
        _Pragma("unroll")                                                      \
        for (int c = 0; c < 8; ++c)                                            \
            bp[c] = *reinterpret_cast<const f32x4*>(                           \
                bias_b + (size_t)snr * 8192 + m0_ * 8 + (sf + 16 * c) * 4);    \
    }

#define WRITE_BIAS()                                                           \
    {                                                                          \
        _Pragma("unroll")                                                      \
        for (int c = 0; c < 8; ++c) {                                          \
            const int f4 = sf + 16 * c;                                        \
            const int mm = f4 >> 1, h0 = (f4 & 1) * 4;                         \
            bsm[(h0 + 0) * 2178 + mm * 34 + snr] = (__bf16)bp[c].x;            \
            bsm[(h0 + 1) * 2178 + mm * 34 + snr] = (__bf16)bp[c].y;            \
            bsm[(h0 + 2) * 2178 + mm * 34 + snr] = (__bf16)bp[c].z;            \
            bsm[(h0 + 3) * 2178 + mm * 34 + snr] = (__bf16)bp[c].w;            \
        }                                                                      \
    }

#define DMA_K(tt)                                                              \
    {                                                                          \
        const int m0_ = (tt) * 64;                                             \
        _Pragma("unroll")                                                      \
        for (int i = 0; i < 8; ++i)                                            \
            dma16(kbase + (size_t)(m0_ + i * 8 + k_row) * 64 + k_csrc * 8,     \
                  &Ks[w][i * 8][0]);                                           \
    }

    // ---- prologue: round 0 ----
    LOAD_BIAS(0)
    DMA_K(0)
    WRITE_BIAS()              // compiler waits bp's vmcnt
    LOAD_BIAS(1)
    asm volatile("s_waitcnt vmcnt(8)");   // drain K-DMA; keep bias(8)
    __builtin_amdgcn_sched_barrier(0);
    asm volatile("s_waitcnt lgkmcnt(0)");
    __builtin_amdgcn_s_barrier();
    __builtin_amdgcn_sched_barrier(0);

    for (int t = 0; t < 16; ++t) {
        // --- fragment reads for round t (K swizzled b128, bias b64) ---
        bf16x8 kf[4][2];
#pragma unroll
        for (int ct = 0; ct < 4; ++ct)
#pragma unroll
            for (int kc = 0; kc < 2; ++kc) {
                const int mrow = ct * 16 + l16;
                kf[ct][kc] = *reinterpret_cast<const bf16x8*>(
                    &Ks[w][mrow][(((kc * 4 + g) ^ (l16 & 7)) * 8)]);
            }
        bf16x4 bb[2][4];
#pragma unroll
        for (int rf = 0; rf < 2; ++rf)
#pragma unroll
            for (int ct = 0; ct < 4; ++ct)
                bb[rf][ct] = *reinterpret_cast<const bf16x4*>(
                    &bsm[w * 2178 + (ct * 16 + l16) * 34 + rf * 16 + 4 * g]);
        asm volatile("s_waitcnt lgkmcnt(0)");
        __builtin_amdgcn_sched_barrier(0);

        // issue next round's K-DMA (Ks wave-local, reads already in regs)
        const int tn = (t + 1 < 16) ? t + 1 : 15;
        DMA_K(tn)

        // V for this round, straight from L2 to regs
        bf16x8 vp[8];
        {
            const int m0_ = t * 64;
#pragma unroll
            for (int oc = 0; oc < 4; ++oc)
#pragma unroll
                for (int mc = 0; mc < 2; ++mc)
                    vp[oc * 2 + mc] = *reinterpret_cast<const bf16x8*>(
                        vbase + (size_t)(oc * 16 + l16) * 1024 + m0_ + mc * 32 + g * 8);
        }

        __builtin_amdgcn_s_barrier();        // all waves done reading bsm
        __builtin_amdgcn_sched_barrier(0);

        // stage bias round t+1 from regs; refill regs with round t+2
        WRITE_BIAS()
        LOAD_BIAS((t + 2 < 16) ? t + 2 : 15)

        // QK^T (K=64 via 2 kc chunks, 4 ct tiles)
        f32x4 s[2][4] = {};
#pragma unroll
        for (int rf = 0; rf < 2; ++rf)
#pragma unroll
            for (int ct = 0; ct < 4; ++ct) {
                s[rf][ct] = MFMA16(qf[rf][0], kf[ct][0], s[rf][ct]);
                s[rf][ct] = MFMA16(qf[rf][1], kf[ct][1], s[rf][ct]);
            }

        // fixed-max softmax -> psm
#pragma unroll
        for (int rf = 0; rf < 2; ++rf)
#pragma unroll
            for (int ct = 0; ct < 4; ++ct)
#pragma unroll
                for (int reg = 0; reg < 4; ++reg) {
                    const int nr = rf * 16 + 4 * g + reg;
                    float p = __expf(s[rf][ct][reg] + (float)bb[rf][ct][reg] - 16.0f);
                    lrun[rf][reg] += p;
                    psm[w * 2178 + nr * 68 + ct * 16 + l16] = (__bf16)p;
                }
        asm volatile("s_waitcnt lgkmcnt(0)");
        __builtin_amdgcn_sched_barrier(0);

        // P relayout + PV (2 m-chunks)
        bf16x8 pf[2][2];
#pragma unroll
        for (int rf = 0; rf < 2; ++rf)
#pragma unroll
            for (int mc = 0; mc < 2; ++mc)
                pf[rf][mc] = *reinterpret_cast<const bf16x8*>(
                    &psm[w * 2178 + (rf * 16 + l16) * 68 + mc * 32 + g * 8]);
#pragma unroll
        for (int rf = 0; rf < 2; ++rf)
#pragma unroll
            for (int oc = 0; oc < 4; ++oc) {
                o[rf][oc] = MFMA16(pf[rf][0], vp[oc * 2 + 0], o[rf][oc]);
                o[rf][oc] = MFMA16(pf[rf][1], vp[oc * 2 + 1], o[rf][oc]);
            }

        // drain this round's K-DMA (keep the 8 newest bias loads in flight)
        asm volatile("s_waitcnt vmcnt(8)");
        __builtin_amdgcn_sched_barrier(0);
        asm volatile("s_waitcnt lgkmcnt(0)");
        __builtin_amdgcn_s_barrier();        // bsm round t+1 visible
        __builtin_amdgcn_sched_barrier(0);
    }
#undef LOAD_BIAS
#undef WRITE_BIAS
#undef DMA_K

    // epilogue: denominator across the 16 m-lanes
#pragma unroll
    for (int rf = 0; rf < 2; ++rf)
#pragma unroll
        for (int reg = 0; reg < 4; ++reg) {
            float l = lrun[rf][reg];
            l += __shfl_xor(l, 1);
            l += __shfl_xor(l, 2);
            l += __shfl_xor(l, 4);
            l += __shfl_xor(l, 8);
            lrun[rf][reg] = l;
        }

#pragma unroll
    for (int rf = 0; rf < 2; ++rf)
#pragma unroll
        for (int oc = 0; oc < 4; ++oc)
#pragma unroll
            for (int reg = 0; reg < 4; ++reg) {
                int n  = n0 + rf * 16 + 4 * g + reg;
                int dh = oc * 16 + l16;
                float val = o[rf][oc][reg] / lrun[rf][reg];
                ow[((size_t)b * 1024 + n) * 512 + w * 64 + dh] = (__bf16)val;
            }
}

// ---------------------------------------------------------------------------
// Kernel 3: output projection v2 — 128x64 tiles (half the staging barriers
// per output element), 512 blocks = 2/CU.
// ---------------------------------------------------------------------------
__global__ __launch_bounds__(256) void gemm_out(
    const __bf16* __restrict__ a, const float* __restrict__ Wm,
    const float* __restrict__ bm, float* __restrict__ out)
{
    __shared__ __bf16 As[128][40];
    __shared__ __bf16 Bs[64][40];
    const int tid  = threadIdx.x;
    const int lane = tid & 63;
    const int w    = tid >> 6;           // wave = 32-row band
    const int g    = lane >> 4, l16 = lane & 15;
    const int r0   = blockIdx.x * 128;
    const int c0   = blockIdx.y * 64;

    const int sra = tid >> 2, sca = tid & 3;  // A: 64 rows x 4 bf16x8, 2 passes
    const int srb = tid >> 3, scb = tid & 7;  // B: 32 rows x 8 float4, 2 passes

    f32x4 acc[2][4] = {};
    for (int k0 = 0; k0 < 512; k0 += 32) {
        __syncthreads();
        {
#pragma unroll
            for (int j = 0; j < 2; ++j) {
                int r = sra + 64 * j;
                bf16x8 av = *reinterpret_cast<const bf16x8*>(a + (size_t)(r0 + r) * 512 + k0 + sca * 8);
                *reinterpret_cast<bf16x8*>(&As[r][sca * 8]) = av;
            }
#pragma unroll
            for (int j = 0; j < 2; ++j) {
                int r = srb + 32 * j;
                float4 bv = *reinterpret_cast<const float4*>(Wm + (size_t)(c0 + r) * 512 + k0 + scb * 4);
                bf16x4 bp = { (__bf16)bv.x, (__bf16)bv.y, (__bf16)bv.z, (__bf16)bv.w };
                *reinterpret_cast<bf16x4*>(&Bs[r][scb * 4]) = bp;
            }
        }
        __syncthreads();
        bf16x8 af[2], bfr[4];
#pragma unroll
        for (int rt = 0; rt < 2; ++rt)
            af[rt] = *reinterpret_cast<const bf16x8*>(&As[w * 32 + rt * 16 + l16][g * 8]);
#pragma unroll
        for (int ct = 0; ct < 4; ++ct)
            bfr[ct] = *reinterpret_cast<const bf16x8*>(&Bs[ct * 16 + l16][g * 8]);
#pragma unroll
        for (int rt = 0; rt < 2; ++rt)
#pragma unroll
            for (int ct = 0; ct < 4; ++ct)
                acc[rt][ct] = MFMA16(af[rt], bfr[ct], acc[rt][ct]);
    }

#pragma unroll
    for (int rt = 0; rt < 2; ++rt)
#pragma unroll
        for (int ct = 0; ct < 4; ++ct)
#pragma unroll
            for (int reg = 0; reg < 4; ++reg) {
                int r = r0 + w * 32 + rt * 16 + 4 * g + reg;
                int c = c0 + ct * 16 + l16;
                out[(size_t)r * 512 + c] = acc[rt][ct][reg] + bm[c];
            }
}

// ---------------------------------------------------------------------------
extern "C" void kernel_launch(void* const* d_in, const int* in_sizes, int n_in,
                              void* d_out, int out_size, void* d_ws, size_t ws_size,
                              hipStream_t stream)
{
    const float* x    = (const float*)d_in[0];
    const float* bias = (const float*)d_in[1];
    const float* Wq   = (const float*)d_in[2];
    const float* Wk   = (const float*)d_in[3];
    const float* Wv   = (const float*)d_in[4];
    const float* Wm   = (const float*)d_in[5];
    const float* bm   = (const float*)d_in[6];
    float* out = (float*)d_out;

    const size_t SEG = (size_t)8 * 8 * 1024 * 64;   // 4M elems (8 MB bf16) each
    __bf16* qw  = (__bf16*)d_ws;
    __bf16* kw  = qw + SEG;
    __bf16* vtw = kw + SEG;
    __bf16* ow  = vtw + SEG;

    gemm_qkv<<<dim3(128, 8), 256, 0, stream>>>(x, Wq, Wk, Wv, qw, kw, vtw);
    attn_v11<<<dim3(8, 32), 512, 0, stream>>>(qw, kw, vtw, bias, ow);
    gemm_out<<<dim3(64, 8), 256, 0, stream>>>(ow, Wm, bm, out);
}

// Round 18
// 130.626 us; speedup vs baseline: 1.1228x; 1.1228x over previous
//
#include <hip/hip_runtime.h>
#include <hip/hip_bf16.h>

typedef __bf16 bf16x8 __attribute__((ext_vector_type(8)));
typedef __bf16 bf16x4 __attribute__((ext_vector_type(4)));
typedef float  f32x4  __attribute__((ext_vector_type(4)));

#define MFMA16(a, b, c) __builtin_amdgcn_mfma_f32_16x16x32_bf16((a), (b), (c), 0, 0, 0)

typedef const __attribute__((address_space(1))) unsigned int* gas_t;
typedef __attribute__((address_space(3))) unsigned int* las_t;
// DMA global->LDS, 16B/lane, linear LDS dest (base + lane*16).
__device__ __forceinline__ void dma16(const __bf16* g, __bf16* l) {
    __builtin_amdgcn_global_load_lds((gas_t)g, (las_t)l, 16, 0, 0);
}

// Problem constants: B=8, N=1024, D=512, H=8, DH=64

// ---------------------------------------------------------------------------
// Kernel 1: fused QKV projection — ONE pass over x serves all 3 weights.
// q,k: [b][h][n][dh] bf16 (q pre-scaled 0.125).
// v BLOCKED: vt[b][h][mt=n/32][dh][n%32] bf16 — each 32-m tile is 4 KB
// contiguous so attn can DMA it with full-cacheline transfers.
// ---------------------------------------------------------------------------
__global__ __launch_bounds__(256) void gemm_qkv(
    const float* __restrict__ x,
    const float* __restrict__ Wq, const float* __restrict__ Wk,
    const float* __restrict__ Wv,
    __bf16* __restrict__ qo, __bf16* __restrict__ ko, __bf16* __restrict__ vto)
{
    __shared__ __bf16 As[64][40];
    __shared__ __bf16 Bs[3][64][40];
    const int tid  = threadIdx.x;
    const int lane = tid & 63;
    const int wid  = tid >> 6;
    const int g    = lane >> 4, l16 = lane & 15;
    const int wr   = wid >> 1,  wc  = wid & 1;
    const int r0   = blockIdx.x * 64;
    const int c0   = blockIdx.y * 64;
    const float* Ws[3] = { Wq, Wk, Wv };

    const int sr  = tid >> 3;
    const int scq = tid & 7;

    f32x4 acc[3][2][2] = {};

    for (int k0 = 0; k0 < 512; k0 += 32) {
        __syncthreads();
#pragma unroll
        for (int j = 0; j < 2; ++j) {
            const int r = sr + 32 * j;
            float4 av = *reinterpret_cast<const float4*>(x + (size_t)(r0 + r) * 512 + k0 + scq * 4);
            bf16x4 ap = { (__bf16)av.x, (__bf16)av.y, (__bf16)av.z, (__bf16)av.w };
            *reinterpret_cast<bf16x4*>(&As[r][scq * 4]) = ap;
#pragma unroll
            for (int widx = 0; widx < 3; ++widx) {
                float4 bv = *reinterpret_cast<const float4*>(Ws[widx] + (size_t)(c0 + r) * 512 + k0 + scq * 4);
                bf16x4 bp = { (__bf16)bv.x, (__bf16)bv.y, (__bf16)bv.z, (__bf16)bv.w };
                *reinterpret_cast<bf16x4*>(&Bs[widx][r][scq * 4]) = bp;
            }
        }
        __syncthreads();
        bf16x8 af[2];
#pragma unroll
        for (int rt = 0; rt < 2; ++rt)
            af[rt] = *reinterpret_cast<const bf16x8*>(&As[wr * 32 + rt * 16 + l16][g * 8]);
#pragma unroll
        for (int widx = 0; widx < 3; ++widx) {
            bf16x8 bfr[2];
#pragma unroll
            for (int ct = 0; ct < 2; ++ct)
                bfr[ct] = *reinterpret_cast<const bf16x8*>(&Bs[widx][wc * 32 + ct * 16 + l16][g * 8]);
#pragma unroll
            for (int rt = 0; rt < 2; ++rt)
#pragma unroll
                for (int ct = 0; ct < 2; ++ct)
                    acc[widx][rt][ct] = MFMA16(af[rt], bfr[ct], acc[widx][rt][ct]);
        }
    }

#pragma unroll
    for (int widx = 0; widx < 2; ++widx) {
        __bf16* dst = (widx == 0) ? qo : ko;
        const float scale = (widx == 0) ? 0.125f : 1.0f;
#pragma unroll
        for (int rt = 0; rt < 2; ++rt)
#pragma unroll
            for (int ct = 0; ct < 2; ++ct)
#pragma unroll
                for (int reg = 0; reg < 4; ++reg) {
                    int r = r0 + wr * 32 + rt * 16 + 4 * g + reg;
                    int c = c0 + wc * 32 + ct * 16 + l16;
                    float val = acc[widx][rt][ct][reg] * scale;
                    int b = r >> 10, n = r & 1023, h = c >> 6, dh = c & 63;
                    dst[(((size_t)b * 8 + h) * 1024 + n) * 64 + dh] = (__bf16)val;
                }
    }
    // v blocked: vt[((b*8+h)*32 + n/32)*2048 + dh*32 + n%32]
#pragma unroll
    for (int rt = 0; rt < 2; ++rt)
#pragma unroll
        for (int ct = 0; ct < 2; ++ct) {
            int r = r0 + wr * 32 + rt * 16 + 4 * g;      // n base, 4 regs = n..n+3
            int c = c0 + wc * 32 + ct * 16 + l16;
            int b = r >> 10, n = r & 1023, h = c >> 6, dh = c & 63;
            bf16x4 pv = { (__bf16)acc[2][rt][ct][0], (__bf16)acc[2][rt][ct][1],
                          (__bf16)acc[2][rt][ct][2], (__bf16)acc[2][rt][ct][3] };
            size_t addr = (((size_t)(b * 8 + h) * 32 + (n >> 5)) * 64 + dh) * 32 + (n & 31);
            *reinterpret_cast<bf16x4*>(vto + addr) = pv;
        }
}

// ---------------------------------------------------------------------------
// Kernel 2: fused flash attention v12 = R13's v7 + DMA'd blocked V.
// 8 waves = 8 heads, 32 Q-rows, grid (8 b, 32 nt), BK=32.
// - K via global_load_lds + source-XOR swizzle (chunk^row) [v7-proven].
// - V via global_load_lds from BLOCKED layout (1KB contiguous per instr,
//   full cachelines) + source-XOR swizzle (chunk ^ (dh>>1)&3) -> 2-way reads.
// - Bias: coalesced f32x4 nt loads, 2-deep reg pipeline, dbuf LDS
//   [2][8][32][36] -> b64 fragment reads.
// - Fixed-max softmax; counted vmcnt; lgkm-only barriers.  LDS ~121 KB.
// ---------------------------------------------------------------------------
__global__ __launch_bounds__(512, 2) void attn_v12(
    const __bf16* __restrict__ qw, const __bf16* __restrict__ kw,
    const __bf16* __restrict__ vtw, const float* __restrict__ bias,
    __bf16* __restrict__ ow)
{
    __shared__ __align__(16) __bf16 Ks[8][32][64];     // 32 KB swizzled content
    __shared__ __align__(16) __bf16 Vs[8][64][32];     // 32 KB swizzled content
    __shared__ __align__(16) __bf16 bsm[2][8][32][36]; // 36.9 KB [buf][h][m][n]
    __shared__ __bf16 psm[8][32][40];                  // 20.5 KB
    const int tid  = threadIdx.x;
    const int w    = tid >> 6;             // head
    const int lane = tid & 63;
    const int g    = lane >> 4, l16 = lane & 15;
    const int b    = blockIdx.x;
    const int n0   = blockIdx.y * 32;
    const size_t bhs = (size_t)b * 8 + w;

    const __bf16* kbase  = kw  + bhs * 1024 * 64;
    const __bf16* vbase  = vtw + bhs * 32 * 2048;      // blocked tiles
    const float*  bias_b = bias + ((size_t)(b * 1024 + n0)) * 8192;

    const int snr = tid >> 4;     // bias n-row 0..31
    const int sf  = tid & 15;     // bias f32x4 chunk base

    // K DMA lane map (v7-proven)
    const int k_row  = lane >> 3;
    const int k_csrc = (lane & 7) ^ (k_row & 7);
    // V DMA lane map: dh = lane>>2 within 16-row group, chunk = lane&3,
    // source chunk pre-swizzled so LDS-linear + swizzled read are conflict-free
    const int v_dh   = lane >> 2;
    const int v_csrc = (lane & 3) ^ ((lane >> 3) & 3);
    // V read swizzle (per lane): chunk = g ^ ((l16>>1)&3)
    const int v_rsw  = (l16 >> 1) & 3;

    bf16x8 qf[2][2];
#pragma unroll
    for (int rf = 0; rf < 2; ++rf)
#pragma unroll
        for (int kc = 0; kc < 2; ++kc)
            qf[rf][kc] = *reinterpret_cast<const bf16x8*>(
                qw + (bhs * 1024 + n0 + rf * 16 + l16) * 64 + kc * 32 + g * 8);

    f32x4 o[2][4] = {};
    float lrun[2][4] = {};

    f32x4 bpA[4], bpB[4];

#define LOAD_BIAS(dst, tt)                                                     \
    {                                                                          \
        const int m0_ = (tt) * 32;                                             \
        _Pragma("unroll")                                                      \
        for (int c = 0; c < 4; ++c)                                            \
            dst[c] = __builtin_nontemporal_load(reinterpret_cast<const f32x4*>(\
                bias_b + (size_t)snr * 8192 + m0_ * 8 + (sf + 16 * c) * 4));   \
    }

#define WRITE_BIAS(buf, src)                                                   \
    {                                                                          \
        _Pragma("unroll")                                                      \
        for (int c = 0; c < 4; ++c) {                                          \
            const int f4 = sf + 16 * c;                                        \
            const int mm = f4 >> 1, h0 = (f4 & 1) * 4;                         \
            bsm[buf][h0 + 0][mm][snr] = (__bf16)src[c].x;                      \
            bsm[buf][h0 + 1][mm][snr] = (__bf16)src[c].y;                      \
            bsm[buf][h0 + 2][mm][snr] = (__bf16)src[c].z;                      \
            bsm[buf][h0 + 3][mm][snr] = (__bf16)src[c].w;                      \
        }                                                                      \
    }

#define DMA_KV(tt)                                                             \
    {                                                                          \
        const int m0_ = (tt) * 32;                                             \
        _Pragma("unroll")                                                      \
        for (int i = 0; i < 4; ++i)                                            \
            dma16(kbase + (size_t)(m0_ + i * 8 + k_row) * 64 + k_csrc * 8,     \
                  &Ks[w][i * 8][0]);                                           \
        const __bf16* vblk = vbase + (size_t)(tt) * 2048;                      \
        _Pragma("unroll")                                                      \
        for (int i = 0; i < 4; ++i)                                            \
            dma16(vblk + (size_t)(i * 16 + v_dh) * 32 + v_csrc * 8,            \
                  &Vs[w][i * 16][0]);                                          \
    }

    // ---- prologue ----
    LOAD_BIAS(bpA, 0)
    DMA_KV(0)
    WRITE_BIAS(0, bpA)
    LOAD_BIAS(bpA, 1)
    LOAD_BIAS(bpB, 2)
    asm volatile("s_waitcnt vmcnt(8)");   // drain 8 DMAs; keep 8 bias loads
    __builtin_amdgcn_sched_barrier(0);
    asm volatile("s_waitcnt lgkmcnt(0)");
    __builtin_amdgcn_s_barrier();
    __builtin_amdgcn_sched_barrier(0);

#define ATTN_STEP(t, BUF, bpX)                                                 \
    {                                                                          \
        bf16x8 kf[2][2], vf[4];                                                \
        _Pragma("unroll")                                                      \
        for (int ct = 0; ct < 2; ++ct)                                         \
            _Pragma("unroll")                                                  \
            for (int kc = 0; kc < 2; ++kc) {                                   \
                const int mrow = ct * 16 + l16;                                \
                kf[ct][kc] = *reinterpret_cast<const bf16x8*>(                 \
                    &Ks[w][mrow][(((kc * 4 + g) ^ (l16 & 7)) * 8)]);           \
            }                                                                  \
        _Pragma("unroll")                                                      \
        for (int oc = 0; oc < 4; ++oc)                                         \
            vf[oc] = *reinterpret_cast<const bf16x8*>(                         \
                &Vs[w][oc * 16 + l16][(g ^ v_rsw) * 8]);                       \
        bf16x4 bb[2][2];                                                       \
        _Pragma("unroll")                                                      \
        for (int rf = 0; rf < 2; ++rf)                                         \
            _Pragma("unroll")                                                  \
            for (int ct = 0; ct < 2; ++ct)                                     \
                bb[rf][ct] = *reinterpret_cast<const bf16x4*>(                 \
                    &bsm[BUF][w][ct * 16 + l16][rf * 16 + 4 * g]);             \
        /* all LDS reads retired before DMA may overwrite Ks/Vs */             \
        asm volatile("s_waitcnt lgkmcnt(0)");                                  \
        __builtin_amdgcn_sched_barrier(0);                                     \
        DMA_KV((t) + 1 < 32 ? (t) + 1 : 31)                                    \
        f32x4 s[2][2] = {};                                                    \
        _Pragma("unroll")                                                      \
        for (int rf = 0; rf < 2; ++rf)                                         \
            _Pragma("unroll")                                                  \
            for (int ct = 0; ct < 2; ++ct) {                                   \
                s[rf][ct] = MFMA16(qf[rf][0], kf[ct][0], s[rf][ct]);           \
                s[rf][ct] = MFMA16(qf[rf][1], kf[ct][1], s[rf][ct]);           \
            }                                                                  \
        _Pragma("unroll")                                                      \
        for (int rf = 0; rf < 2; ++rf)                                         \
            _Pragma("unroll")                                                  \
            for (int reg = 0; reg < 4; ++reg) {                                \
                const int nr = rf * 16 + 4 * g + reg;                          \
                float p0 = __expf(s[rf][0][reg] + (float)bb[rf][0][reg] - 16.0f); \
                float p1 = __expf(s[rf][1][reg] + (float)bb[rf][1][reg] - 16.0f); \
                lrun[rf][reg] += p0 + p1;                                      \
                psm[w][nr][l16]      = (__bf16)p0;                             \
                psm[w][nr][16 + l16] = (__bf16)p1;                             \
            }                                                                  \
        bf16x8 pf[2];                                                          \
        _Pragma("unroll")                                                      \
        for (int rf = 0; rf < 2; ++rf)                                         \
            pf[rf] = *reinterpret_cast<const bf16x8*>(&psm[w][rf * 16 + l16][g * 8]); \
        _Pragma("unroll")                                                      \
        for (int rf = 0; rf < 2; ++rf)                                         \
            _Pragma("unroll")                                                  \
            for (int oc = 0; oc < 4; ++oc)                                     \
                o[rf][oc] = MFMA16(pf[rf], vf[oc], o[rf][oc]);                 \
        /* stage next bias tile; refill its reg set (2-deep) */                \
        WRITE_BIAS((BUF) ^ 1, bpX)                                             \
        LOAD_BIAS(bpX, (t) + 3 < 32 ? (t) + 3 : 31)                            \
        /* drain this iter's DMAs (keep the 4 newest bias loads) */            \
        asm volatile("s_waitcnt vmcnt(4)");                                    \
        __builtin_amdgcn_sched_barrier(0);                                     \
        asm volatile("s_waitcnt lgkmcnt(0)");                                  \
        __builtin_amdgcn_s_barrier();                                          \
        __builtin_amdgcn_sched_barrier(0);                                     \
    }

    for (int t = 0; t < 32; t += 2) {
        ATTN_STEP(t,     0, bpA)
        ATTN_STEP(t + 1, 1, bpB)
    }
#undef ATTN_STEP
#undef LOAD_BIAS
#undef WRITE_BIAS
#undef DMA_KV

    // epilogue: denominator across the 16 m-lanes
#pragma unroll
    for (int rf = 0; rf < 2; ++rf)
#pragma unroll
        for (int reg = 0; reg < 4; ++reg) {
            float l = lrun[rf][reg];
            l += __shfl_xor(l, 1);
            l += __shfl_xor(l, 2);
            l += __shfl_xor(l, 4);
            l += __shfl_xor(l, 8);
            lrun[rf][reg] = l;
        }

#pragma unroll
    for (int rf = 0; rf < 2; ++rf)
#pragma unroll
        for (int oc = 0; oc < 4; ++oc)
#pragma unroll
            for (int reg = 0; reg < 4; ++reg) {
                int n  = n0 + rf * 16 + 4 * g + reg;
                int dh = oc * 16 + l16;
                float val = o[rf][oc][reg] / lrun[rf][reg];
                ow[((size_t)b * 1024 + n) * 512 + w * 64 + dh] = (__bf16)val;
            }
}

// ---------------------------------------------------------------------------
// Kernel 3: output projection (R16's proven 64x64 version).
// ---------------------------------------------------------------------------
__global__ __launch_bounds__(256) void gemm_out(
    const __bf16* __restrict__ a, const float* __restrict__ Wm,
    const float* __restrict__ bm, float* __restrict__ out)
{
    __shared__ __bf16 As[64][40];
    __shared__ __bf16 Bs[64][40];
    const int tid  = threadIdx.x;
    const int lane = tid & 63;
    const int wid  = tid >> 6;
    const int g    = lane >> 4, l16 = lane & 15;
    const int wr   = wid >> 1,  wc  = wid & 1;
    const int r0   = blockIdx.x * 64;
    const int c0   = blockIdx.y * 64;

    const int sra = tid >> 2, sca = tid & 3;
    const int srb = tid >> 3, scb = tid & 7;

    f32x4 acc[2][2] = {};
    for (int k0 = 0; k0 < 512; k0 += 32) {
        __syncthreads();
        {
            bf16x8 av = *reinterpret_cast<const bf16x8*>(a + (size_t)(r0 + sra) * 512 + k0 + sca * 8);
            *reinterpret_cast<bf16x8*>(&As[sra][sca * 8]) = av;
#pragma unroll
            for (int j = 0; j < 2; ++j) {
                int r = srb + 32 * j;
                float4 bv = *reinterpret_cast<const float4*>(Wm + (size_t)(c0 + r) * 512 + k0 + scb * 4);
                bf16x4 bp = { (__bf16)bv.x, (__bf16)bv.y, (__bf16)bv.z, (__bf16)bv.w };
                *reinterpret_cast<bf16x4*>(&Bs[r][scb * 4]) = bp;
            }
        }
        __syncthreads();
        bf16x8 af[2], bfr[2];
#pragma unroll
        for (int rt = 0; rt < 2; ++rt)
            af[rt] = *reinterpret_cast<const bf16x8*>(&As[wr * 32 + rt * 16 + l16][g * 8]);
#pragma unroll
        for (int ct = 0; ct < 2; ++ct)
            bfr[ct] = *reinterpret_cast<const bf16x8*>(&Bs[wc * 32 + ct * 16 + l16][g * 8]);
#pragma unroll
        for (int rt = 0; rt < 2; ++rt)
#pragma unroll
            for (int ct = 0; ct < 2; ++ct)
                acc[rt][ct] = MFMA16(af[rt], bfr[ct], acc[rt][ct]);
    }

#pragma unroll
    for (int rt = 0; rt < 2; ++rt)
#pragma unroll
        for (int ct = 0; ct < 2; ++ct)
#pragma unroll
            for (int reg = 0; reg < 4; ++reg) {
                int r = r0 + wr * 32 + rt * 16 + 4 * g + reg;
                int c = c0 + wc * 32 + ct * 16 + l16;
                out[(size_t)r * 512 + c] = acc[rt][ct][reg] + bm[c];
            }
}

// ---------------------------------------------------------------------------
extern "C" void kernel_launch(void* const* d_in, const int* in_sizes, int n_in,
                              void* d_out, int out_size, void* d_ws, size_t ws_size,
                              hipStream_t stream)
{
    const float* x    = (const float*)d_in[0];
    const float* bias = (const float*)d_in[1];
    const float* Wq   = (const float*)d_in[2];
    const float* Wk   = (const float*)d_in[3];
    const float* Wv   = (const float*)d_in[4];
    const float* Wm   = (const float*)d_in[5];
    const float* bm   = (const float*)d_in[6];
    float* out = (float*)d_out;

    const size_t SEG = (size_t)8 * 8 * 1024 * 64;   // 4M elems (8 MB bf16) each
    __bf16* qw  = (__bf16*)d_ws;
    __bf16* kw  = qw + SEG;
    __bf16* vtw = kw + SEG;
    __bf16* ow  = vtw + SEG;

    gemm_qkv<<<dim3(128, 8), 256, 0, stream>>>(x, Wq, Wk, Wv, qw, kw, vtw);
    attn_v12<<<dim3(8, 32), 512, 0, stream>>>(qw, kw, vtw, bias, ow);
    gemm_out<<<dim3(128, 8), 256, 0, stream>>>(ow, Wm, bm, out);
}

// Round 19
// 124.391 us; speedup vs baseline: 1.1790x; 1.0501x over previous
//
#include <hip/hip_runtime.h>
#include <hip/hip_bf16.h>

typedef __bf16 bf16x8 __attribute__((ext_vector_type(8)));
typedef __bf16 bf16x4 __attribute__((ext_vector_type(4)));
typedef float  f32x4  __attribute__((ext_vector_type(4)));

#define MFMA16(a, b, c) __builtin_amdgcn_mfma_f32_16x16x32_bf16((a), (b), (c), 0, 0, 0)

typedef const __attribute__((address_space(1))) unsigned int* gas_t;
typedef __attribute__((address_space(3))) unsigned int* las_t;
// DMA global->LDS, 16B/lane, linear LDS dest (base + lane*16).
__device__ __forceinline__ void dma16(const __bf16* g, __bf16* l) {
    __builtin_amdgcn_global_load_lds((gas_t)g, (las_t)l, 16, 0, 0);
}

// Problem constants: B=8, N=1024, D=512, H=8, DH=64

// ---------------------------------------------------------------------------
// Kernel 1: QKV projection, 128x128 tiles (4 waves, each 64x64 = 4x4 MFMA
// tiles; 16 MFMA : 8 b128 LDS reads per wave-step).  One weight per block,
// grid (64 rows, 4 cols x 3 weights); x re-reads hit L2/L3 (16 MB resident).
// q,k: [b][h][n][dh] bf16 (q pre-scaled 0.125).
// v BLOCKED: vt[b][h][mt=n/32][dh][n%32] bf16 (4 KB contiguous tiles).
// ---------------------------------------------------------------------------
__global__ __launch_bounds__(256) void gemm_qkv(
    const float* __restrict__ x,
    const float* __restrict__ Wq, const float* __restrict__ Wk,
    const float* __restrict__ Wv,
    __bf16* __restrict__ qo, __bf16* __restrict__ ko, __bf16* __restrict__ vto)
{
    __shared__ __bf16 As[128][40];
    __shared__ __bf16 Bs[128][40];
    const int tid  = threadIdx.x;
    const int lane = tid & 63;
    const int wid  = tid >> 6;
    const int g    = lane >> 4, l16 = lane & 15;
    const int wr   = wid >> 1,  wc  = wid & 1;
    const int r0   = blockIdx.x * 128;
    const int widx = blockIdx.y >> 2;          // 0=q 1=k 2=v
    const int c0   = (blockIdx.y & 3) * 128;
    const float* W = (widx == 0) ? Wq : (widx == 1 ? Wk : Wv);

    f32x4 acc[4][4] = {};

    for (int k0 = 0; k0 < 512; k0 += 32) {
        __syncthreads();
#pragma unroll
        for (int j = 0; j < 4; ++j) {
            const int idx = tid + 256 * j;
            const int r = idx >> 3, c4 = (idx & 7) * 4;
            f32x4 av = *reinterpret_cast<const f32x4*>(x + (size_t)(r0 + r) * 512 + k0 + c4);
            f32x4 bv = *reinterpret_cast<const f32x4*>(W + (size_t)(c0 + r) * 512 + k0 + c4);
            bf16x4 ap = { (__bf16)av.x, (__bf16)av.y, (__bf16)av.z, (__bf16)av.w };
            bf16x4 bp = { (__bf16)bv.x, (__bf16)bv.y, (__bf16)bv.z, (__bf16)bv.w };
            *reinterpret_cast<bf16x4*>(&As[r][c4]) = ap;
            *reinterpret_cast<bf16x4*>(&Bs[r][c4]) = bp;
        }
        __syncthreads();
        bf16x8 af[4], bfr[4];
#pragma unroll
        for (int i = 0; i < 4; ++i) {
            af[i]  = *reinterpret_cast<const bf16x8*>(&As[wr * 64 + i * 16 + l16][g * 8]);
            bfr[i] = *reinterpret_cast<const bf16x8*>(&Bs[wc * 64 + i * 16 + l16][g * 8]);
        }
#pragma unroll
        for (int i = 0; i < 4; ++i)
#pragma unroll
            for (int j = 0; j < 4; ++j)
                acc[i][j] = MFMA16(af[i], bfr[j], acc[i][j]);
    }

    if (widx == 2) {
        // v blocked: vt[((b*8+h)*32 + n/32)*2048 + dh*32 + n%32]
#pragma unroll
        for (int rt = 0; rt < 4; ++rt)
#pragma unroll
            for (int ct = 0; ct < 4; ++ct) {
                int r = r0 + wr * 64 + rt * 16 + 4 * g;   // n base, regs n..n+3
                int c = c0 + wc * 64 + ct * 16 + l16;
                int b = r >> 10, n = r & 1023, h = c >> 6, dh = c & 63;
                bf16x4 pv = { (__bf16)acc[rt][ct][0], (__bf16)acc[rt][ct][1],
                              (__bf16)acc[rt][ct][2], (__bf16)acc[rt][ct][3] };
                size_t addr = (((size_t)(b * 8 + h) * 32 + (n >> 5)) * 64 + dh) * 32 + (n & 31);
                *reinterpret_cast<bf16x4*>(vto + addr) = pv;
            }
    } else {
        __bf16* dst = (widx == 0) ? qo : ko;
        const float scale = (widx == 0) ? 0.125f : 1.0f;
#pragma unroll
        for (int rt = 0; rt < 4; ++rt)
#pragma unroll
            for (int ct = 0; ct < 4; ++ct)
#pragma unroll
                for (int reg = 0; reg < 4; ++reg) {
                    int r = r0 + wr * 64 + rt * 16 + 4 * g + reg;
                    int c = c0 + wc * 64 + ct * 16 + l16;
                    float val = acc[rt][ct][reg] * scale;
                    int b = r >> 10, n = r & 1023, h = c >> 6, dh = c & 63;
                    dst[(((size_t)b * 8 + h) * 1024 + n) * 64 + dh] = (__bf16)val;
                }
    }
}

// ---------------------------------------------------------------------------
// Kernel 2: fused flash attention v12 (UNCHANGED from R18 best).
// ---------------------------------------------------------------------------
__global__ __launch_bounds__(512, 2) void attn_v12(
    const __bf16* __restrict__ qw, const __bf16* __restrict__ kw,
    const __bf16* __restrict__ vtw, const float* __restrict__ bias,
    __bf16* __restrict__ ow)
{
    __shared__ __align__(16) __bf16 Ks[8][32][64];     // 32 KB swizzled content
    __shared__ __align__(16) __bf16 Vs[8][64][32];     // 32 KB swizzled content
    __shared__ __align__(16) __bf16 bsm[2][8][32][36]; // 36.9 KB [buf][h][m][n]
    __shared__ __bf16 psm[8][32][40];                  // 20.5 KB
    const int tid  = threadIdx.x;
    const int w    = tid >> 6;             // head
    const int lane = tid & 63;
    const int g    = lane >> 4, l16 = lane & 15;
    const int b    = blockIdx.x;
    const int n0   = blockIdx.y * 32;
    const size_t bhs = (size_t)b * 8 + w;

    const __bf16* kbase  = kw  + bhs * 1024 * 64;
    const __bf16* vbase  = vtw + bhs * 32 * 2048;      // blocked tiles
    const float*  bias_b = bias + ((size_t)(b * 1024 + n0)) * 8192;

    const int snr = tid >> 4;     // bias n-row 0..31
    const int sf  = tid & 15;     // bias f32x4 chunk base

    const int k_row  = lane >> 3;
    const int k_csrc = (lane & 7) ^ (k_row & 7);
    const int v_dh   = lane >> 2;
    const int v_csrc = (lane & 3) ^ ((lane >> 3) & 3);
    const int v_rsw  = (l16 >> 1) & 3;

    bf16x8 qf[2][2];
#pragma unroll
    for (int rf = 0; rf < 2; ++rf)
#pragma unroll
        for (int kc = 0; kc < 2; ++kc)
            qf[rf][kc] = *reinterpret_cast<const bf16x8*>(
                qw + (bhs * 1024 + n0 + rf * 16 + l16) * 64 + kc * 32 + g * 8);

    f32x4 o[2][4] = {};
    float lrun[2][4] = {};

    f32x4 bpA[4], bpB[4];

#define LOAD_BIAS(dst, tt)                                                     \
    {                                                                          \
        const int m0_ = (tt) * 32;                                             \
        _Pragma("unroll")                                                      \
        for (int c = 0; c < 4; ++c)                                            \
            dst[c] = __builtin_nontemporal_load(reinterpret_cast<const f32x4*>(\
                bias_b + (size_t)snr * 8192 + m0_ * 8 + (sf + 16 * c) * 4));   \
    }

#define WRITE_BIAS(buf, src)                                                   \
    {                                                                          \
        _Pragma("unroll")                                                      \
        for (int c = 0; c < 4; ++c) {                                          \
            const int f4 = sf + 16 * c;                                        \
            const int mm = f4 >> 1, h0 = (f4 & 1) * 4;                         \
            bsm[buf][h0 + 0][mm][snr] = (__bf16)src[c].x;                      \
            bsm[buf][h0 + 1][mm][snr] = (__bf16)src[c].y;                      \
            bsm[buf][h0 + 2][mm][snr] = (__bf16)src[c].z;                      \
            bsm[buf][h0 + 3][mm][snr] = (__bf16)src[c].w;                      \
        }                                                                      \
    }

#define DMA_KV(tt)                                                             \
    {                                                                          \
        const int m0_ = (tt) * 32;                                             \
        _Pragma("unroll")                                                      \
        for (int i = 0; i < 4; ++i)                                            \
            dma16(kbase + (size_t)(m0_ + i * 8 + k_row) * 64 + k_csrc * 8,     \
                  &Ks[w][i * 8][0]);                                           \
        const __bf16* vblk = vbase + (size_t)(tt) * 2048;                      \
        _Pragma("unroll")                                                      \
        for (int i = 0; i < 4; ++i)                                            \
            dma16(vblk + (size_t)(i * 16 + v_dh) * 32 + v_csrc * 8,            \
                  &Vs[w][i * 16][0]);                                          \
    }

    // ---- prologue ----
    LOAD_BIAS(bpA, 0)
    DMA_KV(0)
    WRITE_BIAS(0, bpA)
    LOAD_BIAS(bpA, 1)
    LOAD_BIAS(bpB, 2)
    asm volatile("s_waitcnt vmcnt(8)");   // drain 8 DMAs; keep 8 bias loads
    __builtin_amdgcn_sched_barrier(0);
    asm volatile("s_waitcnt lgkmcnt(0)");
    __builtin_amdgcn_s_barrier();
    __builtin_amdgcn_sched_barrier(0);

#define ATTN_STEP(t, BUF, bpX)                                                 \
    {                                                                          \
        bf16x8 kf[2][2], vf[4];                                                \
        _Pragma("unroll")                                                      \
        for (int ct = 0; ct < 2; ++ct)                                         \
            _Pragma("unroll")                                                  \
            for (int kc = 0; kc < 2; ++kc) {                                   \
                const int mrow = ct * 16 + l16;                                \
                kf[ct][kc] = *reinterpret_cast<const bf16x8*>(                 \
                    &Ks[w][mrow][(((kc * 4 + g) ^ (l16 & 7)) * 8)]);           \
            }                                                                  \
        _Pragma("unroll")                                                      \
        for (int oc = 0; oc < 4; ++oc)                                         \
            vf[oc] = *reinterpret_cast<const bf16x8*>(                         \
                &Vs[w][oc * 16 + l16][(g ^ v_rsw) * 8]);                       \
        bf16x4 bb[2][2];                                                       \
        _Pragma("unroll")                                                      \
        for (int rf = 0; rf < 2; ++rf)                                         \
            _Pragma("unroll")                                                  \
            for (int ct = 0; ct < 2; ++ct)                                     \
                bb[rf][ct] = *reinterpret_cast<const bf16x4*>(                 \
                    &bsm[BUF][w][ct * 16 + l16][rf * 16 + 4 * g]);             \
        /* all LDS reads retired before DMA may overwrite Ks/Vs */             \
        asm volatile("s_waitcnt lgkmcnt(0)");                                  \
        __builtin_amdgcn_sched_barrier(0);                                     \
        DMA_KV((t) + 1 < 32 ? (t) + 1 : 31)                                    \
        f32x4 s[2][2] = {};                                                    \
        _Pragma("unroll")                                                      \
        for (int rf = 0; rf < 2; ++rf)                                         \
            _Pragma("unroll")                                                  \
            for (int ct = 0; ct < 2; ++ct) {                                   \
                s[rf][ct] = MFMA16(qf[rf][0], kf[ct][0], s[rf][ct]);           \
                s[rf][ct] = MFMA16(qf[rf][1], kf[ct][1], s[rf][ct]);           \
            }                                                                  \
        _Pragma("unroll")                                                      \
        for (int rf = 0; rf < 2; ++rf)                                         \
            _Pragma("unroll")                                                  \
            for (int reg = 0; reg < 4; ++reg) {                                \
                const int nr = rf * 16 + 4 * g + reg;                          \
                float p0 = __expf(s[rf][0][reg] + (float)bb[rf][0][reg] - 16.0f); \
                float p1 = __expf(s[rf][1][reg] + (float)bb[rf][1][reg] - 16.0f); \
                lrun[rf][reg] += p0 + p1;                                      \
                psm[w][nr][l16]      = (__bf16)p0;                             \
                psm[w][nr][16 + l16] = (__bf16)p1;                             \
            }                                                                  \
        bf16x8 pf[2];                                                          \
        _Pragma("unroll")                                                      \
        for (int rf = 0; rf < 2; ++rf)                                         \
            pf[rf] = *reinterpret_cast<const bf16x8*>(&psm[w][rf * 16 + l16][g * 8]); \
        _Pragma("unroll")                                                      \
        for (int rf = 0; rf < 2; ++rf)                                         \
            _Pragma("unroll")                                                  \
            for (int oc = 0; oc < 4; ++oc)                                     \
                o[rf][oc] = MFMA16(pf[rf], vf[oc], o[rf][oc]);                 \
        /* stage next bias tile; refill its reg set (2-deep) */                \
        WRITE_BIAS((BUF) ^ 1, bpX)                                             \
        LOAD_BIAS(bpX, (t) + 3 < 32 ? (t) + 3 : 31)                            \
        /* drain this iter's DMAs (keep the 4 newest bias loads) */            \
        asm volatile("s_waitcnt vmcnt(4)");                                    \
        __builtin_amdgcn_sched_barrier(0);                                     \
        asm volatile("s_waitcnt lgkmcnt(0)");                                  \
        __builtin_amdgcn_s_barrier();                                          \
        __builtin_amdgcn_sched_barrier(0);                                     \
    }

    for (int t = 0; t < 32; t += 2) {
        ATTN_STEP(t,     0, bpA)
        ATTN_STEP(t + 1, 1, bpB)
    }
#undef ATTN_STEP
#undef LOAD_BIAS
#undef WRITE_BIAS
#undef DMA_KV

    // epilogue: denominator across the 16 m-lanes
#pragma unroll
    for (int rf = 0; rf < 2; ++rf)
#pragma unroll
        for (int reg = 0; reg < 4; ++reg) {
            float l = lrun[rf][reg];
            l += __shfl_xor(l, 1);
            l += __shfl_xor(l, 2);
            l += __shfl_xor(l, 4);
            l += __shfl_xor(l, 8);
            lrun[rf][reg] = l;
        }

#pragma unroll
    for (int rf = 0; rf < 2; ++rf)
#pragma unroll
        for (int oc = 0; oc < 4; ++oc)
#pragma unroll
            for (int reg = 0; reg < 4; ++reg) {
                int n  = n0 + rf * 16 + 4 * g + reg;
                int dh = oc * 16 + l16;
                float val = o[rf][oc][reg] / lrun[rf][reg];
                ow[((size_t)b * 1024 + n) * 512 + w * 64 + dh] = (__bf16)val;
            }
}

// ---------------------------------------------------------------------------
// Kernel 3: output projection, 128x128 tiles (same shape as kernel 1).
// Grid (64, 4).  A = ow bf16 (staged directly), B = Wm f32 -> bf16.
// ---------------------------------------------------------------------------
__global__ __launch_bounds__(256) void gemm_out(
    const __bf16* __restrict__ a, const float* __restrict__ Wm,
    const float* __restrict__ bm, float* __restrict__ out)
{
    __shared__ __bf16 As[128][40];
    __shared__ __bf16 Bs[128][40];
    const int tid  = threadIdx.x;
    const int lane = tid & 63;
    const int wid  = tid >> 6;
    const int g    = lane >> 4, l16 = lane & 15;
    const int wr   = wid >> 1,  wc  = wid & 1;
    const int r0   = blockIdx.x * 128;
    const int c0   = blockIdx.y * 128;

    f32x4 acc[4][4] = {};

    for (int k0 = 0; k0 < 512; k0 += 32) {
        __syncthreads();
#pragma unroll
        for (int j = 0; j < 2; ++j) {
            const int idx = tid + 256 * j;
            const int r = idx >> 2, c8 = (idx & 3) * 8;
            bf16x8 av = *reinterpret_cast<const bf16x8*>(a + (size_t)(r0 + r) * 512 + k0 + c8);
            *reinterpret_cast<bf16x8*>(&As[r][c8]) = av;
        }
#pragma unroll
        for (int j = 0; j < 4; ++j) {
            const int idx = tid + 256 * j;
            const int r = idx >> 3, c4 = (idx & 7) * 4;
            f32x4 bv = *reinterpret_cast<const f32x4*>(Wm + (size_t)(c0 + r) * 512 + k0 + c4);
            bf16x4 bp = { (__bf16)bv.x, (__bf16)bv.y, (__bf16)bv.z, (__bf16)bv.w };
            *reinterpret_cast<bf16x4*>(&Bs[r][c4]) = bp;
        }
        __syncthreads();
        bf16x8 af[4], bfr[4];
#pragma unroll
        for (int i = 0; i < 4; ++i) {
            af[i]  = *reinterpret_cast<const bf16x8*>(&As[wr * 64 + i * 16 + l16][g * 8]);
            bfr[i] = *reinterpret_cast<const bf16x8*>(&Bs[wc * 64 + i * 16 + l16][g * 8]);
        }
#pragma unroll
        for (int i = 0; i < 4; ++i)
#pragma unroll
            for (int j = 0; j < 4; ++j)
                acc[i][j] = MFMA16(af[i], bfr[j], acc[i][j]);
    }

#pragma unroll
    for (int rt = 0; rt < 4; ++rt)
#pragma unroll
        for (int ct = 0; ct < 4; ++ct)
#pragma unroll
            for (int reg = 0; reg < 4; ++reg) {
                int r = r0 + wr * 64 + rt * 16 + 4 * g + reg;
                int c = c0 + wc * 64 + ct * 16 + l16;
                out[(size_t)r * 512 + c] = acc[rt][ct][reg] + bm[c];
            }
}

// ---------------------------------------------------------------------------
extern "C" void kernel_launch(void* const* d_in, const int* in_sizes, int n_in,
                              void* d_out, int out_size, void* d_ws, size_t ws_size,
                              hipStream_t stream)
{
    const float* x    = (const float*)d_in[0];
    const float* bias = (const float*)d_in[1];
    const float* Wq   = (const float*)d_in[2];
    const float* Wk   = (const float*)d_in[3];
    const float* Wv   = (const float*)d_in[4];
    const float* Wm   = (const float*)d_in[5];
    const float* bm   = (const float*)d_in[6];
    float* out = (float*)d_out;

    const size_t SEG = (size_t)8 * 8 * 1024 * 64;   // 4M elems (8 MB bf16) each
    __bf16* qw  = (__bf16*)d_ws;
    __bf16* kw  = qw + SEG;
    __bf16* vtw = kw + SEG;
    __bf16* ow  = vtw + SEG;

    gemm_qkv<<<dim3(64, 12), 256, 0, stream>>>(x, Wq, Wk, Wv, qw, kw, vtw);
    attn_v12<<<dim3(8, 32), 512, 0, stream>>>(qw, kw, vtw, bias, ow);
    gemm_out<<<dim3(64, 4), 256, 0, stream>>>(ow, Wm, bm, out);
}

// Round 20
// 120.865 us; speedup vs baseline: 1.2134x; 1.0292x over previous
//
#include <hip/hip_runtime.h>
#include <hip/hip_bf16.h>

typedef __bf16 bf16x8 __attribute__((ext_vector_type(8)));
typedef __bf16 bf16x4 __attribute__((ext_vector_type(4)));
typedef float  f32x4  __attribute__((ext_vector_type(4)));

#define MFMA16(a, b, c) __builtin_amdgcn_mfma_f32_16x16x32_bf16((a), (b), (c), 0, 0, 0)

typedef const __attribute__((address_space(1))) unsigned int* gas_t;
typedef __attribute__((address_space(3))) unsigned int* las_t;
// DMA global->LDS, 16B/lane, linear LDS dest (base + lane*16).
__device__ __forceinline__ void dma16(const __bf16* g, __bf16* l) {
    __builtin_amdgcn_global_load_lds((gas_t)g, (las_t)l, 16, 0, 0);
}

// Problem constants: B=8, N=1024, D=512, H=8, DH=64

// ---------------------------------------------------------------------------
// Kernel 1: QKV projection, 128x128 tiles (R19-proven).
// q,k: [b][h][n][dh] bf16 (q pre-scaled 0.125).
// v BLOCKED: vt[b][h][mt=n/32][dh][n%32] bf16 (4 KB contiguous tiles).
// ---------------------------------------------------------------------------
__global__ __launch_bounds__(256) void gemm_qkv(
    const float* __restrict__ x,
    const float* __restrict__ Wq, const float* __restrict__ Wk,
    const float* __restrict__ Wv,
    __bf16* __restrict__ qo, __bf16* __restrict__ ko, __bf16* __restrict__ vto)
{
    __shared__ __bf16 As[128][40];
    __shared__ __bf16 Bs[128][40];
    const int tid  = threadIdx.x;
    const int lane = tid & 63;
    const int wid  = tid >> 6;
    const int g    = lane >> 4, l16 = lane & 15;
    const int wr   = wid >> 1,  wc  = wid & 1;
    const int r0   = blockIdx.x * 128;
    const int widx = blockIdx.y >> 2;          // 0=q 1=k 2=v
    const int c0   = (blockIdx.y & 3) * 128;
    const float* W = (widx == 0) ? Wq : (widx == 1 ? Wk : Wv);

    f32x4 acc[4][4] = {};

    for (int k0 = 0; k0 < 512; k0 += 32) {
        __syncthreads();
#pragma unroll
        for (int j = 0; j < 4; ++j) {
            const int idx = tid + 256 * j;
            const int r = idx >> 3, c4 = (idx & 7) * 4;
            f32x4 av = *reinterpret_cast<const f32x4*>(x + (size_t)(r0 + r) * 512 + k0 + c4);
            f32x4 bv = *reinterpret_cast<const f32x4*>(W + (size_t)(c0 + r) * 512 + k0 + c4);
            bf16x4 ap = { (__bf16)av.x, (__bf16)av.y, (__bf16)av.z, (__bf16)av.w };
            bf16x4 bp = { (__bf16)bv.x, (__bf16)bv.y, (__bf16)bv.z, (__bf16)bv.w };
            *reinterpret_cast<bf16x4*>(&As[r][c4]) = ap;
            *reinterpret_cast<bf16x4*>(&Bs[r][c4]) = bp;
        }
        __syncthreads();
        bf16x8 af[4], bfr[4];
#pragma unroll
        for (int i = 0; i < 4; ++i) {
            af[i]  = *reinterpret_cast<const bf16x8*>(&As[wr * 64 + i * 16 + l16][g * 8]);
            bfr[i] = *reinterpret_cast<const bf16x8*>(&Bs[wc * 64 + i * 16 + l16][g * 8]);
        }
#pragma unroll
        for (int i = 0; i < 4; ++i)
#pragma unroll
            for (int j = 0; j < 4; ++j)
                acc[i][j] = MFMA16(af[i], bfr[j], acc[i][j]);
    }

    if (widx == 2) {
        // v blocked: vt[((b*8+h)*32 + n/32)*2048 + dh*32 + n%32]
#pragma unroll
        for (int rt = 0; rt < 4; ++rt)
#pragma unroll
            for (int ct = 0; ct < 4; ++ct) {
                int r = r0 + wr * 64 + rt * 16 + 4 * g;   // n base, regs n..n+3
                int c = c0 + wc * 64 + ct * 16 + l16;
                int b = r >> 10, n = r & 1023, h = c >> 6, dh = c & 63;
                bf16x4 pv = { (__bf16)acc[rt][ct][0], (__bf16)acc[rt][ct][1],
                              (__bf16)acc[rt][ct][2], (__bf16)acc[rt][ct][3] };
                size_t addr = (((size_t)(b * 8 + h) * 32 + (n >> 5)) * 64 + dh) * 32 + (n & 31);
                *reinterpret_cast<bf16x4*>(vto + addr) = pv;
            }
    } else {
        __bf16* dst = (widx == 0) ? qo : ko;
        const float scale = (widx == 0) ? 0.125f : 1.0f;
#pragma unroll
        for (int rt = 0; rt < 4; ++rt)
#pragma unroll
            for (int ct = 0; ct < 4; ++ct)
#pragma unroll
                for (int reg = 0; reg < 4; ++reg) {
                    int r = r0 + wr * 64 + rt * 16 + 4 * g + reg;
                    int c = c0 + wc * 64 + ct * 16 + l16;
                    float val = acc[rt][ct][reg] * scale;
                    int b = r >> 10, n = r & 1023, h = c >> 6, dh = c & 63;
                    dst[(((size_t)b * 8 + h) * 1024 + n) * 64 + dh] = (__bf16)val;
                }
    }
}

// ---------------------------------------------------------------------------
// Kernel 2: fused flash attention v13 = v12 + s_setprio(1) around MFMA
// clusters (T5; waves are head-independent between barriers -> role
// diversity for the CU scheduler).  Otherwise byte-identical to R18/R19.
// ---------------------------------------------------------------------------
__global__ __launch_bounds__(512, 2) void attn_v13(
    const __bf16* __restrict__ qw, const __bf16* __restrict__ kw,
    const __bf16* __restrict__ vtw, const float* __restrict__ bias,
    __bf16* __restrict__ ow)
{
    __shared__ __align__(16) __bf16 Ks[8][32][64];     // 32 KB swizzled content
    __shared__ __align__(16) __bf16 Vs[8][64][32];     // 32 KB swizzled content
    __shared__ __align__(16) __bf16 bsm[2][8][32][36]; // 36.9 KB [buf][h][m][n]
    __shared__ __bf16 psm[8][32][40];                  // 20.5 KB
    const int tid  = threadIdx.x;
    const int w    = tid >> 6;             // head
    const int lane = tid & 63;
    const int g    = lane >> 4, l16 = lane & 15;
    const int b    = blockIdx.x;
    const int n0   = blockIdx.y * 32;
    const size_t bhs = (size_t)b * 8 + w;

    const __bf16* kbase  = kw  + bhs * 1024 * 64;
    const __bf16* vbase  = vtw + bhs * 32 * 2048;      // blocked tiles
    const float*  bias_b = bias + ((size_t)(b * 1024 + n0)) * 8192;

    const int snr = tid >> 4;     // bias n-row 0..31
    const int sf  = tid & 15;     // bias f32x4 chunk base

    const int k_row  = lane >> 3;
    const int k_csrc = (lane & 7) ^ (k_row & 7);
    const int v_dh   = lane >> 2;
    const int v_csrc = (lane & 3) ^ ((lane >> 3) & 3);
    const int v_rsw  = (l16 >> 1) & 3;

    bf16x8 qf[2][2];
#pragma unroll
    for (int rf = 0; rf < 2; ++rf)
#pragma unroll
        for (int kc = 0; kc < 2; ++kc)
            qf[rf][kc] = *reinterpret_cast<const bf16x8*>(
                qw + (bhs * 1024 + n0 + rf * 16 + l16) * 64 + kc * 32 + g * 8);

    f32x4 o[2][4] = {};
    float lrun[2][4] = {};

    f32x4 bpA[4], bpB[4];

#define LOAD_BIAS(dst, tt)                                                     \
    {                                                                          \
        const int m0_ = (tt) * 32;                                             \
        _Pragma("unroll")                                                      \
        for (int c = 0; c < 4; ++c)                                            \
            dst[c] = __builtin_nontemporal_load(reinterpret_cast<const f32x4*>(\
                bias_b + (size_t)snr * 8192 + m0_ * 8 + (sf + 16 * c) * 4));   \
    }

#define WRITE_BIAS(buf, src)                                                   \
    {                                                                          \
        _Pragma("unroll")                                                      \
        for (int c = 0; c < 4; ++c) {                                          \
            const int f4 = sf + 16 * c;                                        \
            const int mm = f4 >> 1, h0 = (f4 & 1) * 4;                         \
            bsm[buf][h0 + 0][mm][snr] = (__bf16)src[c].x;                      \
            bsm[buf][h0 + 1][mm][snr] = (__bf16)src[c].y;                      \
            bsm[buf][h0 + 2][mm][snr] = (__bf16)src[c].z;                      \
            bsm[buf][h0 + 3][mm][snr] = (__bf16)src[c].w;                      \
        }                                                                      \
    }

#define DMA_KV(tt)                                                             \
    {                                                                          \
        const int m0_ = (tt) * 32;                                             \
        _Pragma("unroll")                                                      \
        for (int i = 0; i < 4; ++i)                                            \
            dma16(kbase + (size_t)(m0_ + i * 8 + k_row) * 64 + k_csrc * 8,     \
                  &Ks[w][i * 8][0]);                                           \
        const __bf16* vblk = vbase + (size_t)(tt) * 2048;                      \
        _Pragma("unroll")                                                      \
        for (int i = 0; i < 4; ++i)                                            \
            dma16(vblk + (size_t)(i * 16 + v_dh) * 32 + v_csrc * 8,            \
                  &Vs[w][i * 16][0]);                                          \
    }

    // ---- prologue ----
    LOAD_BIAS(bpA, 0)
    DMA_KV(0)
    WRITE_BIAS(0, bpA)
    LOAD_BIAS(bpA, 1)
    LOAD_BIAS(bpB, 2)
    asm volatile("s_waitcnt vmcnt(8)");   // drain 8 DMAs; keep 8 bias loads
    __builtin_amdgcn_sched_barrier(0);
    asm volatile("s_waitcnt lgkmcnt(0)");
    __builtin_amdgcn_s_barrier();
    __builtin_amdgcn_sched_barrier(0);

#define ATTN_STEP(t, BUF, bpX)                                                 \
    {                                                                          \
        bf16x8 kf[2][2], vf[4];                                                \
        _Pragma("unroll")                                                      \
        for (int ct = 0; ct < 2; ++ct)                                         \
            _Pragma("unroll")                                                  \
            for (int kc = 0; kc < 2; ++kc) {                                   \
                const int mrow = ct * 16 + l16;                                \
                kf[ct][kc] = *reinterpret_cast<const bf16x8*>(                 \
                    &Ks[w][mrow][(((kc * 4 + g) ^ (l16 & 7)) * 8)]);           \
            }                                                                  \
        _Pragma("unroll")                                                      \
        for (int oc = 0; oc < 4; ++oc)                                         \
            vf[oc] = *reinterpret_cast<const bf16x8*>(                         \
                &Vs[w][oc * 16 + l16][(g ^ v_rsw) * 8]);                       \
        bf16x4 bb[2][2];                                                       \
        _Pragma("unroll")                                                      \
        for (int rf = 0; rf < 2; ++rf)                                         \
            _Pragma("unroll")                                                  \
            for (int ct = 0; ct < 2; ++ct)                                     \
                bb[rf][ct] = *reinterpret_cast<const bf16x4*>(                 \
                    &bsm[BUF][w][ct * 16 + l16][rf * 16 + 4 * g]);             \
        /* all LDS reads retired before DMA may overwrite Ks/Vs */             \
        asm volatile("s_waitcnt lgkmcnt(0)");                                  \
        __builtin_amdgcn_sched_barrier(0);                                     \
        DMA_KV((t) + 1 < 32 ? (t) + 1 : 31)                                    \
        f32x4 s[2][2] = {};                                                    \
        __builtin_amdgcn_s_setprio(1);                                         \
        _Pragma("unroll")                                                      \
        for (int rf = 0; rf < 2; ++rf)                                         \
            _Pragma("unroll")                                                  \
            for (int ct = 0; ct < 2; ++ct) {                                   \
                s[rf][ct] = MFMA16(qf[rf][0], kf[ct][0], s[rf][ct]);           \
                s[rf][ct] = MFMA16(qf[rf][1], kf[ct][1], s[rf][ct]);           \
            }                                                                  \
        __builtin_amdgcn_s_setprio(0);                                         \
        _Pragma("unroll")                                                      \
        for (int rf = 0; rf < 2; ++rf)                                         \
            _Pragma("unroll")                                                  \
            for (int reg = 0; reg < 4; ++reg) {                                \
                const int nr = rf * 16 + 4 * g + reg;                          \
                float p0 = __expf(s[rf][0][reg] + (float)bb[rf][0][reg] - 16.0f); \
                float p1 = __expf(s[rf][1][reg] + (float)bb[rf][1][reg] - 16.0f); \
                lrun[rf][reg] += p0 + p1;                                      \
                psm[w][nr][l16]      = (__bf16)p0;                             \
                psm[w][nr][16 + l16] = (__bf16)p1;                             \
            }                                                                  \
        bf16x8 pf[2];                                                          \
        _Pragma("unroll")                                                      \
        for (int rf = 0; rf < 2; ++rf)                                         \
            pf[rf] = *reinterpret_cast<const bf16x8*>(&psm[w][rf * 16 + l16][g * 8]); \
        __builtin_amdgcn_s_setprio(1);                                         \
        _Pragma("unroll")                                                      \
        for (int rf = 0; rf < 2; ++rf)                                         \
            _Pragma("unroll")                                                  \
            for (int oc = 0; oc < 4; ++oc)                                     \
                o[rf][oc] = MFMA16(pf[rf], vf[oc], o[rf][oc]);                 \
        __builtin_amdgcn_s_setprio(0);                                         \
        /* stage next bias tile; refill its reg set (2-deep) */                \
        WRITE_BIAS((BUF) ^ 1, bpX)                                             \
        LOAD_BIAS(bpX, (t) + 3 < 32 ? (t) + 3 : 31)                            \
        /* drain this iter's DMAs (keep the 4 newest bias loads) */            \
        asm volatile("s_waitcnt vmcnt(4)");                                    \
        __builtin_amdgcn_sched_barrier(0);                                     \
        asm volatile("s_waitcnt lgkmcnt(0)");                                  \
        __builtin_amdgcn_s_barrier();                                          \
        __builtin_amdgcn_sched_barrier(0);                                     \
    }

    for (int t = 0; t < 32; t += 2) {
        ATTN_STEP(t,     0, bpA)
        ATTN_STEP(t + 1, 1, bpB)
    }
#undef ATTN_STEP
#undef LOAD_BIAS
#undef WRITE_BIAS
#undef DMA_KV

    // epilogue: denominator across the 16 m-lanes
#pragma unroll
    for (int rf = 0; rf < 2; ++rf)
#pragma unroll
        for (int reg = 0; reg < 4; ++reg) {
            float l = lrun[rf][reg];
            l += __shfl_xor(l, 1);
            l += __shfl_xor(l, 2);
            l += __shfl_xor(l, 4);
            l += __shfl_xor(l, 8);
            lrun[rf][reg] = l;
        }

#pragma unroll
    for (int rf = 0; rf < 2; ++rf)
#pragma unroll
        for (int oc = 0; oc < 4; ++oc)
#pragma unroll
            for (int reg = 0; reg < 4; ++reg) {
                int n  = n0 + rf * 16 + 4 * g + reg;
                int dh = oc * 16 + l16;
                float val = o[rf][oc][reg] / lrun[rf][reg];
                ow[((size_t)b * 1024 + n) * 512 + w * 64 + dh] = (__bf16)val;
            }
}

// ---------------------------------------------------------------------------
// Kernel 3: output projection, 128x128 tiles (R19-proven).
// ---------------------------------------------------------------------------
__global__ __launch_bounds__(256) void gemm_out(
    const __bf16* __restrict__ a, const float* __restrict__ Wm,
    const float* __restrict__ bm, float* __restrict__ out)
{
    __shared__ __bf16 As[128][40];
    __shared__ __bf16 Bs[128][40];
    const int tid  = threadIdx.x;
    const int lane = tid & 63;
    const int wid  = tid >> 6;
    const int g    = lane >> 4, l16 = lane & 15;
    const int wr   = wid >> 1,  wc  = wid & 1;
    const int r0   = blockIdx.x * 128;
    const int c0   = blockIdx.y * 128;

    f32x4 acc[4][4] = {};

    for (int k0 = 0; k0 < 512; k0 += 32) {
        __syncthreads();
#pragma unroll
        for (int j = 0; j < 2; ++j) {
            const int idx = tid + 256 * j;
            const int r = idx >> 2, c8 = (idx & 3) * 8;
            bf16x8 av = *reinterpret_cast<const bf16x8*>(a + (size_t)(r0 + r) * 512 + k0 + c8);
            *reinterpret_cast<bf16x8*>(&As[r][c8]) = av;
        }
#pragma unroll
        for (int j = 0; j < 4; ++j) {
            const int idx = tid + 256 * j;
            const int r = idx >> 3, c4 = (idx & 7) * 4;
            f32x4 bv = *reinterpret_cast<const f32x4*>(Wm + (size_t)(c0 + r) * 512 + k0 + c4);
            bf16x4 bp = { (__bf16)bv.x, (__bf16)bv.y, (__bf16)bv.z, (__bf16)bv.w };
            *reinterpret_cast<bf16x4*>(&Bs[r][c4]) = bp;
        }
        __syncthreads();
        bf16x8 af[4], bfr[4];
#pragma unroll
        for (int i = 0; i < 4; ++i) {
            af[i]  = *reinterpret_cast<const bf16x8*>(&As[wr * 64 + i * 16 + l16][g * 8]);
            bfr[i] = *reinterpret_cast<const bf16x8*>(&Bs[wc * 64 + i * 16 + l16][g * 8]);
        }
#pragma unroll
        for (int i = 0; i < 4; ++i)
#pragma unroll
            for (int j = 0; j < 4; ++j)
                acc[i][j] = MFMA16(af[i], bfr[j], acc[i][j]);
    }

#pragma unroll
    for (int rt = 0; rt < 4; ++rt)
#pragma unroll
        for (int ct = 0; ct < 4; ++ct)
#pragma unroll
            for (int reg = 0; reg < 4; ++reg) {
                int r = r0 + wr * 64 + rt * 16 + 4 * g + reg;
                int c = c0 + wc * 64 + ct * 16 + l16;
                out[(size_t)r * 512 + c] = acc[rt][ct][reg] + bm[c];
            }
}

// ---------------------------------------------------------------------------
extern "C" void kernel_launch(void* const* d_in, const int* in_sizes, int n_in,
                              void* d_out, int out_size, void* d_ws, size_t ws_size,
                              hipStream_t stream)
{
    const float* x    = (const float*)d_in[0];
    const float* bias = (const float*)d_in[1];
    const float* Wq   = (const float*)d_in[2];
    const float* Wk   = (const float*)d_in[3];
    const float* Wv   = (const float*)d_in[4];
    const float* Wm   = (const float*)d_in[5];
    const float* bm   = (const float*)d_in[6];
    float* out = (float*)d_out;

    const size_t SEG = (size_t)8 * 8 * 1024 * 64;   // 4M elems (8 MB bf16) each
    __bf16* qw  = (__bf16*)d_ws;
    __bf16* kw  = qw + SEG;
    __bf16* vtw = kw + SEG;
    __bf16* ow  = vtw + SEG;

    gemm_qkv<<<dim3(64, 12), 256, 0, stream>>>(x, Wq, Wk, Wv, qw, kw, vtw);
    attn_v13<<<dim3(8, 32), 512, 0, stream>>>(qw, kw, vtw, bias, ow);
    gemm_out<<<dim3(64, 4), 256, 0, stream>>>(ow, Wm, bm, out);
}

// Round 21
// 114.522 us; speedup vs baseline: 1.2807x; 1.0554x over previous
//
#include <hip/hip_runtime.h>
#include <hip/hip_bf16.h>

typedef __bf16 bf16x8 __attribute__((ext_vector_type(8)));
typedef __bf16 bf16x4 __attribute__((ext_vector_type(4)));
typedef float  f32x4  __attribute__((ext_vector_type(4)));

#define MFMA16(a, b, c) __builtin_amdgcn_mfma_f32_16x16x32_bf16((a), (b), (c), 0, 0, 0)

typedef const __attribute__((address_space(1))) unsigned int* gas_t;
typedef __attribute__((address_space(3))) unsigned int* las_t;
// DMA global->LDS, 16B/lane, linear LDS dest (base + lane*16).
__device__ __forceinline__ void dma16(const __bf16* g, __bf16* l) {
    __builtin_amdgcn_global_load_lds((gas_t)g, (las_t)l, 16, 0, 0);
}

// LDS-visibility barrier that does NOT drain outstanding global loads.
__device__ __forceinline__ void barrier_lds_only() {
    asm volatile("s_waitcnt lgkmcnt(0)" ::: "memory");
    __builtin_amdgcn_s_barrier();
    __builtin_amdgcn_sched_barrier(0);
}

// Problem constants: B=8, N=1024, D=512, H=8, DH=64

// ---------------------------------------------------------------------------
// Kernel 1: QKV projection, 128x128 tiles + PIPELINED k-loop (dbuf LDS,
// 1-deep reg prefetch, lgkm-only barrier -> no vmcnt(0) drain per step).
// q,k: [b][h][n][dh] bf16 (q pre-scaled 0.125).
// v BLOCKED: vt[b][h][mt=n/32][dh][n%32] bf16 (4 KB contiguous tiles).
// ---------------------------------------------------------------------------
__global__ __launch_bounds__(256) void gemm_qkv(
    const float* __restrict__ x,
    const float* __restrict__ Wq, const float* __restrict__ Wk,
    const float* __restrict__ Wv,
    __bf16* __restrict__ qo, __bf16* __restrict__ ko, __bf16* __restrict__ vto)
{
    __shared__ __bf16 As[2][128][40];
    __shared__ __bf16 Bs[2][128][40];
    const int tid  = threadIdx.x;
    const int lane = tid & 63;
    const int wid  = tid >> 6;
    const int g    = lane >> 4, l16 = lane & 15;
    const int wr   = wid >> 1,  wc  = wid & 1;
    const int r0   = blockIdx.x * 128;
    const int widx = blockIdx.y >> 2;          // 0=q 1=k 2=v
    const int c0   = (blockIdx.y & 3) * 128;
    const float* W = (widx == 0) ? Wq : (widx == 1 ? Wk : Wv);

    f32x4 acc[4][4] = {};
    f32x4 av[4], bv[4];

#define QKV_LOAD(ks)                                                           \
    {                                                                          \
        const int k0_ = (ks) * 32;                                             \
        _Pragma("unroll")                                                      \
        for (int j = 0; j < 4; ++j) {                                          \
            const int idx = tid + 256 * j;                                     \
            const int r = idx >> 3, c4 = (idx & 7) * 4;                        \
            av[j] = *reinterpret_cast<const f32x4*>(x + (size_t)(r0 + r) * 512 + k0_ + c4); \
            bv[j] = *reinterpret_cast<const f32x4*>(W + (size_t)(c0 + r) * 512 + k0_ + c4); \
        }                                                                      \
    }

#define QKV_WRITE(buf)                                                         \
    {                                                                          \
        _Pragma("unroll")                                                      \
        for (int j = 0; j < 4; ++j) {                                          \
            const int idx = tid + 256 * j;                                     \
            const int r = idx >> 3, c4 = (idx & 7) * 4;                        \
            bf16x4 ap = { (__bf16)av[j].x, (__bf16)av[j].y, (__bf16)av[j].z, (__bf16)av[j].w }; \
            bf16x4 bp = { (__bf16)bv[j].x, (__bf16)bv[j].y, (__bf16)bv[j].z, (__bf16)bv[j].w }; \
            *reinterpret_cast<bf16x4*>(&As[buf][r][c4]) = ap;                  \
            *reinterpret_cast<bf16x4*>(&Bs[buf][r][c4]) = bp;                  \
        }                                                                      \
    }

#define QKV_STEP(ks, BUF)                                                      \
    {                                                                          \
        bf16x8 af[4], bfr[4];                                                  \
        _Pragma("unroll")                                                      \
        for (int i = 0; i < 4; ++i) {                                          \
            af[i]  = *reinterpret_cast<const bf16x8*>(&As[BUF][wr * 64 + i * 16 + l16][g * 8]); \
            bfr[i] = *reinterpret_cast<const bf16x8*>(&Bs[BUF][wc * 64 + i * 16 + l16][g * 8]); \
        }                                                                      \
        _Pragma("unroll")                                                      \
        for (int i = 0; i < 4; ++i)                                            \
            _Pragma("unroll")                                                  \
            for (int j = 0; j < 4; ++j)                                        \
                acc[i][j] = MFMA16(af[i], bfr[j], acc[i][j]);                  \
        QKV_WRITE((BUF) ^ 1)           /* regs loaded 1 iter ago: counted */   \
        QKV_LOAD((ks) + 2 < 16 ? (ks) + 2 : 15)                                \
        barrier_lds_only();                                                    \
    }

    // prologue
    QKV_LOAD(0)
    QKV_WRITE(0)
    QKV_LOAD(1)
    __syncthreads();

    for (int ks = 0; ks < 16; ks += 2) {
        QKV_STEP(ks,     0)
        QKV_STEP(ks + 1, 1)
    }
#undef QKV_STEP
#undef QKV_LOAD
#undef QKV_WRITE

    if (widx == 2) {
        // v blocked: vt[((b*8+h)*32 + n/32)*2048 + dh*32 + n%32]
#pragma unroll
        for (int rt = 0; rt < 4; ++rt)
#pragma unroll
            for (int ct = 0; ct < 4; ++ct) {
                int r = r0 + wr * 64 + rt * 16 + 4 * g;   // n base, regs n..n+3
                int c = c0 + wc * 64 + ct * 16 + l16;
                int b = r >> 10, n = r & 1023, h = c >> 6, dh = c & 63;
                bf16x4 pv = { (__bf16)acc[rt][ct][0], (__bf16)acc[rt][ct][1],
                              (__bf16)acc[rt][ct][2], (__bf16)acc[rt][ct][3] };
                size_t addr = (((size_t)(b * 8 + h) * 32 + (n >> 5)) * 64 + dh) * 32 + (n & 31);
                *reinterpret_cast<bf16x4*>(vto + addr) = pv;
            }
    } else {
        __bf16* dst = (widx == 0) ? qo : ko;
        const float scale = (widx == 0) ? 0.125f : 1.0f;
#pragma unroll
        for (int rt = 0; rt < 4; ++rt)
#pragma unroll
            for (int ct = 0; ct < 4; ++ct)
#pragma unroll
                for (int reg = 0; reg < 4; ++reg) {
                    int r = r0 + wr * 64 + rt * 16 + 4 * g + reg;
                    int c = c0 + wc * 64 + ct * 16 + l16;
                    float val = acc[rt][ct][reg] * scale;
                    int b = r >> 10, n = r & 1023, h = c >> 6, dh = c & 63;
                    dst[(((size_t)b * 8 + h) * 1024 + n) * 64 + dh] = (__bf16)val;
                }
    }
}

// ---------------------------------------------------------------------------
// Kernel 2: fused flash attention v13 (UNCHANGED from R20 best).
// ---------------------------------------------------------------------------
__global__ __launch_bounds__(512, 2) void attn_v13(
    const __bf16* __restrict__ qw, const __bf16* __restrict__ kw,
    const __bf16* __restrict__ vtw, const float* __restrict__ bias,
    __bf16* __restrict__ ow)
{
    __shared__ __align__(16) __bf16 Ks[8][32][64];     // 32 KB swizzled content
    __shared__ __align__(16) __bf16 Vs[8][64][32];     // 32 KB swizzled content
    __shared__ __align__(16) __bf16 bsm[2][8][32][36]; // 36.9 KB [buf][h][m][n]
    __shared__ __bf16 psm[8][32][40];                  // 20.5 KB
    const int tid  = threadIdx.x;
    const int w    = tid >> 6;             // head
    const int lane = tid & 63;
    const int g    = lane >> 4, l16 = lane & 15;
    const int b    = blockIdx.x;
    const int n0   = blockIdx.y * 32;
    const size_t bhs = (size_t)b * 8 + w;

    const __bf16* kbase  = kw  + bhs * 1024 * 64;
    const __bf16* vbase  = vtw + bhs * 32 * 2048;      // blocked tiles
    const float*  bias_b = bias + ((size_t)(b * 1024 + n0)) * 8192;

    const int snr = tid >> 4;     // bias n-row 0..31
    const int sf  = tid & 15;     // bias f32x4 chunk base

    const int k_row  = lane >> 3;
    const int k_csrc = (lane & 7) ^ (k_row & 7);
    const int v_dh   = lane >> 2;
    const int v_csrc = (lane & 3) ^ ((lane >> 3) & 3);
    const int v_rsw  = (l16 >> 1) & 3;

    bf16x8 qf[2][2];
#pragma unroll
    for (int rf = 0; rf < 2; ++rf)
#pragma unroll
        for (int kc = 0; kc < 2; ++kc)
            qf[rf][kc] = *reinterpret_cast<const bf16x8*>(
                qw + (bhs * 1024 + n0 + rf * 16 + l16) * 64 + kc * 32 + g * 8);

    f32x4 o[2][4] = {};
    float lrun[2][4] = {};

    f32x4 bpA[4], bpB[4];

#define LOAD_BIAS(dst, tt)                                                     \
    {                                                                          \
        const int m0_ = (tt) * 32;                                             \
        _Pragma("unroll")                                                      \
        for (int c = 0; c < 4; ++c)                                            \
            dst[c] = __builtin_nontemporal_load(reinterpret_cast<const f32x4*>(\
                bias_b + (size_t)snr * 8192 + m0_ * 8 + (sf + 16 * c) * 4));   \
    }

#define WRITE_BIAS(buf, src)                                                   \
    {                                                                          \
        _Pragma("unroll")                                                      \
        for (int c = 0; c < 4; ++c) {                                          \
            const int f4 = sf + 16 * c;                                        \
            const int mm = f4 >> 1, h0 = (f4 & 1) * 4;                         \
            bsm[buf][h0 + 0][mm][snr] = (__bf16)src[c].x;                      \
            bsm[buf][h0 + 1][mm][snr] = (__bf16)src[c].y;                      \
            bsm[buf][h0 + 2][mm][snr] = (__bf16)src[c].z;                      \
            bsm[buf][h0 + 3][mm][snr] = (__bf16)src[c].w;                      \
        }                                                                      \
    }

#define DMA_KV(tt)                                                             \
    {                                                                          \
        const int m0_ = (tt) * 32;                                             \
        _Pragma("unroll")                                                      \
        for (int i = 0; i < 4; ++i)                                            \
            dma16(kbase + (size_t)(m0_ + i * 8 + k_row) * 64 + k_csrc * 8,     \
                  &Ks[w][i * 8][0]);                                           \
        const __bf16* vblk = vbase + (size_t)(tt) * 2048;                      \
        _Pragma("unroll")                                                      \
        for (int i = 0; i < 4; ++i)                                            \
            dma16(vblk + (size_t)(i * 16 + v_dh) * 32 + v_csrc * 8,            \
                  &Vs[w][i * 16][0]);                                          \
    }

    // ---- prologue ----
    LOAD_BIAS(bpA, 0)
    DMA_KV(0)
    WRITE_BIAS(0, bpA)
    LOAD_BIAS(bpA, 1)
    LOAD_BIAS(bpB, 2)
    asm volatile("s_waitcnt vmcnt(8)");   // drain 8 DMAs; keep 8 bias loads
    __builtin_amdgcn_sched_barrier(0);
    asm volatile("s_waitcnt lgkmcnt(0)");
    __builtin_amdgcn_s_barrier();
    __builtin_amdgcn_sched_barrier(0);

#define ATTN_STEP(t, BUF, bpX)                                                 \
    {                                                                          \
        bf16x8 kf[2][2], vf[4];                                                \
        _Pragma("unroll")                                                      \
        for (int ct = 0; ct < 2; ++ct)                                         \
            _Pragma("unroll")                                                  \
            for (int kc = 0; kc < 2; ++kc) {                                   \
                const int mrow = ct * 16 + l16;                                \
                kf[ct][kc] = *reinterpret_cast<const bf16x8*>(                 \
                    &Ks[w][mrow][(((kc * 4 + g) ^ (l16 & 7)) * 8)]);           \
            }                                                                  \
        _Pragma("unroll")                                                      \
        for (int oc = 0; oc < 4; ++oc)                                         \
            vf[oc] = *reinterpret_cast<const bf16x8*>(                         \
                &Vs[w][oc * 16 + l16][(g ^ v_rsw) * 8]);                       \
        bf16x4 bb[2][2];                                                       \
        _Pragma("unroll")                                                      \
        for (int rf = 0; rf < 2; ++rf)                                         \
            _Pragma("unroll")                                                  \
            for (int ct = 0; ct < 2; ++ct)                                     \
                bb[rf][ct] = *reinterpret_cast<const bf16x4*>(                 \
                    &bsm[BUF][w][ct * 16 + l16][rf * 16 + 4 * g]);             \
        /* all LDS reads retired before DMA may overwrite Ks/Vs */             \
        asm volatile("s_waitcnt lgkmcnt(0)");                                  \
        __builtin_amdgcn_sched_barrier(0);                                     \
        DMA_KV((t) + 1 < 32 ? (t) + 1 : 31)                                    \
        f32x4 s[2][2] = {};                                                    \
        __builtin_amdgcn_s_setprio(1);                                         \
        _Pragma("unroll")                                                      \
        for (int rf = 0; rf < 2; ++rf)                                         \
            _Pragma("unroll")                                                  \
            for (int ct = 0; ct < 2; ++ct) {                                   \
                s[rf][ct] = MFMA16(qf[rf][0], kf[ct][0], s[rf][ct]);           \
                s[rf][ct] = MFMA16(qf[rf][1], kf[ct][1], s[rf][ct]);           \
            }                                                                  \
        __builtin_amdgcn_s_setprio(0);                                         \
        _Pragma("unroll")                                                      \
        for (int rf = 0; rf < 2; ++rf)                                         \
            _Pragma("unroll")                                                  \
            for (int reg = 0; reg < 4; ++reg) {                                \
                const int nr = rf * 16 + 4 * g + reg;                          \
                float p0 = __expf(s[rf][0][reg] + (float)bb[rf][0][reg] - 16.0f); \
                float p1 = __expf(s[rf][1][reg] + (float)bb[rf][1][reg] - 16.0f); \
                lrun[rf][reg] += p0 + p1;                                      \
                psm[w][nr][l16]      = (__bf16)p0;                             \
                psm[w][nr][16 + l16] = (__bf16)p1;                             \
            }                                                                  \
        bf16x8 pf[2];                                                          \
        _Pragma("unroll")                                                      \
        for (int rf = 0; rf < 2; ++rf)                                         \
            pf[rf] = *reinterpret_cast<const bf16x8*>(&psm[w][rf * 16 + l16][g * 8]); \
        __builtin_amdgcn_s_setprio(1);                                         \
        _Pragma("unroll")                                                      \
        for (int rf = 0; rf < 2; ++rf)                                         \
            _Pragma("unroll")                                                  \
            for (int oc = 0; oc < 4; ++oc)                                     \
                o[rf][oc] = MFMA16(pf[rf], vf[oc], o[rf][oc]);                 \
        __builtin_amdgcn_s_setprio(0);                                         \
        /* stage next bias tile; refill its reg set (2-deep) */                \
        WRITE_BIAS((BUF) ^ 1, bpX)                                             \
        LOAD_BIAS(bpX, (t) + 3 < 32 ? (t) + 3 : 31)                            \
        /* drain this iter's DMAs (keep the 4 newest bias loads) */            \
        asm volatile("s_waitcnt vmcnt(4)");                                    \
        __builtin_amdgcn_sched_barrier(0);                                     \
        asm volatile("s_waitcnt lgkmcnt(0)");                                  \
        __builtin_amdgcn_s_barrier();                                          \
        __builtin_amdgcn_sched_barrier(0);                                     \
    }

    for (int t = 0; t < 32; t += 2) {
        ATTN_STEP(t,     0, bpA)
        ATTN_STEP(t + 1, 1, bpB)
    }
#undef ATTN_STEP
#undef LOAD_BIAS
#undef WRITE_BIAS
#undef DMA_KV

    // epilogue: denominator across the 16 m-lanes
#pragma unroll
    for (int rf = 0; rf < 2; ++rf)
#pragma unroll
        for (int reg = 0; reg < 4; ++reg) {
            float l = lrun[rf][reg];
            l += __shfl_xor(l, 1);
            l += __shfl_xor(l, 2);
            l += __shfl_xor(l, 4);
            l += __shfl_xor(l, 8);
            lrun[rf][reg] = l;
        }

#pragma unroll
    for (int rf = 0; rf < 2; ++rf)
#pragma unroll
        for (int oc = 0; oc < 4; ++oc)
#pragma unroll
            for (int reg = 0; reg < 4; ++reg) {
                int n  = n0 + rf * 16 + 4 * g + reg;
                int dh = oc * 16 + l16;
                float val = o[rf][oc][reg] / lrun[rf][reg];
                ow[((size_t)b * 1024 + n) * 512 + w * 64 + dh] = (__bf16)val;
            }
}

// ---------------------------------------------------------------------------
// Kernel 3: output projection, 128x128 tiles + PIPELINED k-loop.
// ---------------------------------------------------------------------------
__global__ __launch_bounds__(256) void gemm_out(
    const __bf16* __restrict__ a, const float* __restrict__ Wm,
    const float* __restrict__ bm, float* __restrict__ out)
{
    __shared__ __bf16 As[2][128][40];
    __shared__ __bf16 Bs[2][128][40];
    const int tid  = threadIdx.x;
    const int lane = tid & 63;
    const int wid  = tid >> 6;
    const int g    = lane >> 4, l16 = lane & 15;
    const int wr   = wid >> 1,  wc  = wid & 1;
    const int r0   = blockIdx.x * 128;
    const int c0   = blockIdx.y * 128;

    f32x4 acc[4][4] = {};
    bf16x8 avp[2];
    f32x4  bvp[4];

#define OUT_LOAD(ks)                                                           \
    {                                                                          \
        const int k0_ = (ks) * 32;                                             \
        _Pragma("unroll")                                                      \
        for (int j = 0; j < 2; ++j) {                                          \
            const int idx = tid + 256 * j;                                     \
            const int r = idx >> 2, c8 = (idx & 3) * 8;                        \
            avp[j] = *reinterpret_cast<const bf16x8*>(a + (size_t)(r0 + r) * 512 + k0_ + c8); \
        }                                                                      \
        _Pragma("unroll")                                                      \
        for (int j = 0; j < 4; ++j) {                                          \
            const int idx = tid + 256 * j;                                     \
            const int r = idx >> 3, c4 = (idx & 7) * 4;                        \
            bvp[j] = *reinterpret_cast<const f32x4*>(Wm + (size_t)(c0 + r) * 512 + k0_ + c4); \
        }                                                                      \
    }

#define OUT_WRITE(buf)                                                         \
    {                                                                          \
        _Pragma("unroll")                                                      \
        for (int j = 0; j < 2; ++j) {                                          \
            const int idx = tid + 256 * j;                                     \
            const int r = idx >> 2, c8 = (idx & 3) * 8;                        \
            *reinterpret_cast<bf16x8*>(&As[buf][r][c8]) = avp[j];              \
        }                                                                      \
        _Pragma("unroll")                                                      \
        for (int j = 0; j < 4; ++j) {                                          \
            const int idx = tid + 256 * j;                                     \
            const int r = idx >> 3, c4 = (idx & 7) * 4;                        \
            bf16x4 bp = { (__bf16)bvp[j].x, (__bf16)bvp[j].y, (__bf16)bvp[j].z, (__bf16)bvp[j].w }; \
            *reinterpret_cast<bf16x4*>(&Bs[buf][r][c4]) = bp;                  \
        }                                                                      \
    }

#define OUT_STEP(ks, BUF)                                                      \
    {                                                                          \
        bf16x8 af[4], bfr[4];                                                  \
        _Pragma("unroll")                                                      \
        for (int i = 0; i < 4; ++i) {                                          \
            af[i]  = *reinterpret_cast<const bf16x8*>(&As[BUF][wr * 64 + i * 16 + l16][g * 8]); \
            bfr[i] = *reinterpret_cast<const bf16x8*>(&Bs[BUF][wc * 64 + i * 16 + l16][g * 8]); \
        }                                                                      \
        _Pragma("unroll")                                                      \
        for (int i = 0; i < 4; ++i)                                            \
            _Pragma("unroll")                                                  \
            for (int j = 0; j < 4; ++j)                                        \
                acc[i][j] = MFMA16(af[i], bfr[j], acc[i][j]);                  \
        OUT_WRITE((BUF) ^ 1)                                                   \
        OUT_LOAD((ks) + 2 < 16 ? (ks) + 2 : 15)                                \
        barrier_lds_only();                                                    \
    }

    OUT_LOAD(0)
    OUT_WRITE(0)
    OUT_LOAD(1)
    __syncthreads();

    for (int ks = 0; ks < 16; ks += 2) {
        OUT_STEP(ks,     0)
        OUT_STEP(ks + 1, 1)
    }
#undef OUT_STEP
#undef OUT_LOAD
#undef OUT_WRITE

#pragma unroll
    for (int rt = 0; rt < 4; ++rt)
#pragma unroll
        for (int ct = 0; ct < 4; ++ct)
#pragma unroll
            for (int reg = 0; reg < 4; ++reg) {
                int r = r0 + wr * 64 + rt * 16 + 4 * g + reg;
                int c = c0 + wc * 64 + ct * 16 + l16;
                out[(size_t)r * 512 + c] = acc[rt][ct][reg] + bm[c];
            }
}

// ---------------------------------------------------------------------------
extern "C" void kernel_launch(void* const* d_in, const int* in_sizes, int n_in,
                              void* d_out, int out_size, void* d_ws, size_t ws_size,
                              hipStream_t stream)
{
    const float* x    = (const float*)d_in[0];
    const float* bias = (const float*)d_in[1];
    const float* Wq   = (const float*)d_in[2];
    const float* Wk   = (const float*)d_in[3];
    const float* Wv   = (const float*)d_in[4];
    const float* Wm   = (const float*)d_in[5];
    const float* bm   = (const float*)d_in[6];
    float* out = (float*)d_out;

    const size_t SEG = (size_t)8 * 8 * 1024 * 64;   // 4M elems (8 MB bf16) each
    __bf16* qw  = (__bf16*)d_ws;
    __bf16* kw  = qw + SEG;
    __bf16* vtw = kw + SEG;
    __bf16* ow  = vtw + SEG;

    gemm_qkv<<<dim3(64, 12), 256, 0, stream>>>(x, Wq, Wk, Wv, qw, kw, vtw);
    attn_v13<<<dim3(8, 32), 512, 0, stream>>>(qw, kw, vtw, bias, ow);
    gemm_out<<<dim3(64, 4), 256, 0, stream>>>(ow, Wm, bm, out);
}